// Round 12
// baseline (1604.920 us; speedup 1.0000x reference)
//
#include <hip/hip_runtime.h>
#include <stdint.h>

// ---------- types / helpers ----------
typedef unsigned short u16t;
typedef u16t us4 __attribute__((ext_vector_type(4)));
typedef u16t us8 __attribute__((ext_vector_type(8)));
typedef __bf16 bf8v __attribute__((ext_vector_type(8)));
typedef float f4 __attribute__((ext_vector_type(4)));

#define MFMA(a, b, c) __builtin_amdgcn_mfma_f32_16x16x32_bf16((a), (b), (c), 0, 0, 0)
#define GLOAD_LDS16(g, l) __builtin_amdgcn_global_load_lds( \
    (const __attribute__((address_space(1))) void*)(g),     \
    (__attribute__((address_space(3))) void*)(l), 16, 0, 0)

__device__ __forceinline__ float bf2f(u16t u) {
  union { unsigned int i; float f; } c; c.i = ((unsigned int)u) << 16; return c.f;
}
__device__ __forceinline__ u16t f2bf(float f) {
  union { float f; unsigned int i; } c; c.f = f;
  return (u16t)((c.i + 0x7FFFu + ((c.i >> 16) & 1u)) >> 16);
}
__device__ __forceinline__ float wsum(float v) {
#pragma unroll
  for (int o = 32; o > 0; o >>= 1) v += __shfl_xor(v, o);
  return v;
}
__device__ __forceinline__ float wmax(float v) {
#pragma unroll
  for (int o = 32; o > 0; o >>= 1) v = fmaxf(v, __shfl_xor(v, o));
  return v;
}

// ---------- pack hid+Wq+Wk+Wv f32->bf16 in one launch ----------
__global__ __launch_bounds__(256) void pack_all(const float* __restrict__ hid,
    const float* __restrict__ Wq, const float* __restrict__ Wk, const float* __restrict__ Wv,
    u16t* __restrict__ hidb, u16t* __restrict__ wqb, u16t* __restrict__ wkb,
    u16t* __restrict__ wvb) {
  const int g = blockIdx.x * 256 + threadIdx.x;  // grid covers 2883584 groups
  const float* src; u16t* dst; int off;
  if (g < 2097152) { src = hid; dst = hidb; off = g; }
  else if (g < 2359296) { src = Wq; dst = wqb; off = g - 2097152; }
  else if (g < 2621440) { src = Wk; dst = wkb; off = g - 2359296; }
  else { src = Wv; dst = wvb; off = g - 2621440; }
  f4 v = *(const f4*)&src[(size_t)off * 4];
  us4 o;
#pragma unroll
  for (int e = 0; e < 4; ++e) o[e] = f2bf(v[e]);
  *(us4*)&dst[(size_t)off * 4] = o;
}

// ---------- GEMM (all-bf16 operands): C[M,N] = A[M,K] @ Bt[N,K]^T ----------
// global_load_lds width=16 staging. LDS LINEAR [128][32]. EPI==1: bias+GELU.
template <bool CF32, int EPI>
__device__ __forceinline__ void gemm_body(const u16t* __restrict__ A,
    const u16t* __restrict__ Bt, void* __restrict__ Cv, const float* __restrict__ bias,
    int K, int lda, int ldb, int ldc, int m0, int n0) {
  __shared__ u16t As[128][32];
  __shared__ u16t Bs[128][32];
  const int tid = threadIdx.x;
  const int wv = tid >> 6, l = tid & 63;
  const int wr = wv >> 1, wc = wv & 1;
  const int lr = l & 15, kg8 = (l >> 4) * 8, rg4 = (l >> 4) * 4;
  const f4 zf = {0.f, 0.f, 0.f, 0.f};
  f4 acc[4][4];
#pragma unroll
  for (int i = 0; i < 4; ++i)
#pragma unroll
    for (int j = 0; j < 4; ++j) acc[i][j] = zf;

  const u16t* ga = A + (size_t)(m0 + wv * 32 + (l >> 2)) * lda + (l & 3) * 8;
  const u16t* gb = Bt + (size_t)(n0 + wv * 32 + (l >> 2)) * ldb + (l & 3) * 8;
  u16t* la0 = &As[wv * 32][0];
  u16t* la1 = &As[wv * 32 + 16][0];
  u16t* lb0 = &Bs[wv * 32][0];
  u16t* lb1 = &Bs[wv * 32 + 16][0];

  for (int kt = 0; kt < K; kt += 32) {
    GLOAD_LDS16(ga + kt, la0);
    GLOAD_LDS16(ga + (size_t)16 * lda + kt, la1);
    GLOAD_LDS16(gb + kt, lb0);
    GLOAD_LDS16(gb + (size_t)16 * ldb + kt, lb1);
    __syncthreads();
    bf8v af[4], bg[4];
#pragma unroll
    for (int f = 0; f < 4; ++f) af[f] = *(const bf8v*)&As[wr * 64 + f * 16 + lr][kg8];
#pragma unroll
    for (int f = 0; f < 4; ++f) bg[f] = *(const bf8v*)&Bs[wc * 64 + f * 16 + lr][kg8];
#pragma unroll
    for (int i = 0; i < 4; ++i)
#pragma unroll
      for (int j = 0; j < 4; ++j) acc[i][j] = MFMA(af[i], bg[j], acc[i][j]);
    __syncthreads();
  }
#pragma unroll
  for (int i = 0; i < 4; ++i) {
    const int rb = m0 + wr * 64 + i * 16 + rg4;
#pragma unroll
    for (int j = 0; j < 4; ++j) {
      const int cb = n0 + wc * 64 + j * 16 + lr;
#pragma unroll
      for (int r = 0; r < 4; ++r) {
        float x = acc[i][j][r];
        if (EPI == 1) {
          float xx = x + ((cb < 2288) ? bias[cb] : 0.f);
          x = 0.5f * xx * (1.f + erff(xx * 0.70710678118f));
        }
        if (CF32)
          ((float*)Cv)[(size_t)(rb + r) * ldc + cb] = x;
        else
          ((u16t*)Cv)[(size_t)(rb + r) * ldc + cb] = f2bf(x);
      }
    }
  }
}

template <bool CF32, int EPI>
__global__ __launch_bounds__(256) void gemm_bt(const u16t* __restrict__ Av,
    const u16t* __restrict__ Btv, void* __restrict__ Cv, const float* __restrict__ bias,
    int K, int lda, int ldb, int ldc) {
  gemm_body<CF32, EPI>(Av, Btv, Cv, bias, K, lda, ldb, ldc,
                       blockIdx.y * 128, blockIdx.x * 128);
}

__global__ __launch_bounds__(256) void gemm_qkv3(const u16t* __restrict__ A,
    const u16t* __restrict__ B0, const u16t* __restrict__ B1,
    const u16t* __restrict__ B2, u16t* __restrict__ C0, u16t* __restrict__ C1,
    u16t* __restrict__ C2v) {
  const int z = blockIdx.z;
  const u16t* Bt = (z == 0) ? B0 : ((z == 1) ? B1 : B2);
  u16t* C = (z == 0) ? C0 : ((z == 1) ? C1 : C2v);
  gemm_body<false, 0>(A, Bt, C, nullptr, 1024, 1024, 1024, 1024,
                      blockIdx.y * 128, blockIdx.x * 128);
}

// ---------- depthwise causal conv K=4 + SiLU (sliding-window registers) ----------
__global__ __launch_bounds__(256) void conv4_silu(
    const u16t* __restrict__ qlin, const u16t* __restrict__ klin, const u16t* __restrict__ vlin,
    const float* __restrict__ wq, const float* __restrict__ wk, const float* __restrict__ wvv,
    u16t* __restrict__ qc, u16t* __restrict__ kc, u16t* __restrict__ vc) {
  const int tid = threadIdx.x;
  const int l0 = blockIdx.x * 64;
  const int b = blockIdx.y >> 2, cb = blockIdx.y & 3;
  const int z = blockIdx.z;
  const u16t* in_ = (z == 0) ? qlin : ((z == 1) ? klin : vlin);
  const float* w_ = (z == 0) ? wq : ((z == 1) ? wk : wvv);
  u16t* out_ = (z == 0) ? qc : ((z == 1) ? kc : vc);
  const int c = cb * 256 + tid;
  __shared__ u16t sm[67][256];
  for (int i = 0; i < 67; ++i) {
    int ls = l0 - 3 + i;
    sm[i][tid] = (ls >= 0) ? in_[((size_t)b * 4096 + ls) * 1024 + c] : (u16t)0;
  }
  __syncthreads();
  f4 w4 = *(const f4*)&w_[c * 4];
  float x0 = bf2f(sm[0][tid]), x1 = bf2f(sm[1][tid]), x2 = bf2f(sm[2][tid]);
  for (int ll = 0; ll < 64; ++ll) {
    float x3 = bf2f(sm[ll + 3][tid]);
    float y = x0 * w4[0] + x1 * w4[1] + x2 * w4[2] + x3 * w4[3];
    y = y / (1.f + expf(-y));
    out_[((size_t)b * 4096 + l0 + ll) * 1024 + c] = f2bf(y);
    x0 = x1; x1 = x2; x2 = x3;
  }
}

// ---------- fused beta + l2norm(q,k) + kb/vb ----------
__global__ __launch_bounds__(256) void prep_kernel(u16t* __restrict__ qc, u16t* __restrict__ kc,
    const u16t* __restrict__ vc, const float* __restrict__ hid, const float* __restrict__ Wb,
    u16t* __restrict__ kbeta, u16t* __restrict__ vbeta) {
  const int m = blockIdx.x, tid = threadIdx.x;
  const int h = tid >> 6, l = tid & 63;
  float bacc = 0.f;
#pragma unroll
  for (int it = 0; it < 4; ++it) {
    int kk = l * 4 + it * 256;
    f4 hv = *(const f4*)&hid[(size_t)m * 1024 + kk];
    f4 wv4 = *(const f4*)&Wb[(size_t)h * 1024 + kk];
#pragma unroll
    for (int e = 0; e < 4; ++e) bacc += hv[e] * wv4[e];
  }
  const float bet = 1.f / (1.f + expf(-wsum(bacc)));
  const size_t base = (size_t)m * 1024 + h * 256 + l * 4;
  us4 q4 = *(const us4*)&qc[base];
  float qf[4]; float ss = 0.f;
#pragma unroll
  for (int e = 0; e < 4; ++e) { qf[e] = bf2f(q4[e]); ss += qf[e] * qf[e]; }
  float qsc = rsqrtf(wsum(ss) + 1e-12f);
  us4 qo;
#pragma unroll
  for (int e = 0; e < 4; ++e) qo[e] = f2bf(qf[e] * qsc);
  *(us4*)&qc[base] = qo;
  us4 k4 = *(const us4*)&kc[base];
  float kf[4]; ss = 0.f;
#pragma unroll
  for (int e = 0; e < 4; ++e) { kf[e] = bf2f(k4[e]); ss += kf[e] * kf[e]; }
  float ksc = rsqrtf(wsum(ss) + 1e-12f);
  us4 ko, kbo;
#pragma unroll
  for (int e = 0; e < 4; ++e) {
    float kn = kf[e] * ksc;
    ko[e] = f2bf(kn);
    kbo[e] = f2bf(kn * bet);
  }
  *(us4*)&kc[base] = ko;
  *(us4*)&kbeta[base] = kbo;
  us4 v4 = *(const us4*)&vc[base];
  us4 vo;
#pragma unroll
  for (int e = 0; e < 4; ++e) vo[e] = f2bf(bf2f(v4[e]) * bet);
  *(us4*)&vbeta[base] = vo;
}

// ---------- per-chunk triangular inverse, u = T@vb, w = T@kb (MFMA phase 1) ----------
__global__ __launch_bounds__(256) void chunk_uw(const u16t* __restrict__ kn,
    const u16t* __restrict__ kbeta, const u16t* __restrict__ vbeta,
    u16t* __restrict__ ug, u16t* __restrict__ wg) {
  const int tid = threadIdx.x;
  const int bh = blockIdx.x >> 7, ci = blockIdx.x & 127;
  const int b = bh >> 2, h = bh & 3;
  const int l0 = ci * 32;
  __shared__ u16t kns[32][264], kbs[32][264], vbs[32][264];
  __shared__ float attn_s[32][33];
  const int sr = tid >> 5, sd8 = (tid & 31) * 8;
  const size_t rowbase = (size_t)b * 4096 * 1024 + (size_t)h * 256;
#pragma unroll
  for (int i = 0; i < 4; ++i) {
    int r = i * 8 + sr;
    size_t g = rowbase + (size_t)(l0 + r) * 1024 + sd8;
    *(us8*)&kns[r][sd8] = *(const us8*)&kn[g];
    *(us8*)&kbs[r][sd8] = *(const us8*)&kbeta[g];
    *(us8*)&vbs[r][sd8] = *(const us8*)&vbeta[g];
  }
  __syncthreads();
  {  // phase 1 via MFMA: wave wv -> 16x16 tile (rq, rk)
    const int wv = tid >> 6, l = tid & 63;
    const int lr = l & 15, kg8 = (l >> 4) * 8, rg4 = (l >> 4) * 4;
    const int rq = wv >> 1, rk = wv & 1;
    f4 t4 = {0.f, 0.f, 0.f, 0.f};
#pragma unroll
    for (int ks = 0; ks < 8; ++ks) {
      bf8v a = *(const bf8v*)&kbs[rq * 16 + lr][ks * 32 + kg8];
      bf8v bb = *(const bf8v*)&kns[rk * 16 + lr][ks * 32 + kg8];
      t4 = MFMA(a, bb, t4);
    }
    const int colj = rk * 16 + lr;
#pragma unroll
    for (int rr = 0; rr < 4; ++rr) {
      const int rowr = rq * 16 + rg4 + rr;
      attn_s[rowr][colj] = (colj < rowr) ? -t4[rr] : 0.f;
    }
  }
  __syncthreads();
  if (tid < 32) {
    const int j = tid;
    for (int i = 1; i < 32; ++i) {
      float aij = attn_s[i][j];
      float upd = 0.f;
#pragma unroll 1
      for (int k = 1; k < 31; ++k) {
        float aik = __shfl(aij, k);
        float akj = (k > j && k < i) ? attn_s[k][j] : 0.f;
        upd += aik * akj;
      }
      if (j < i) attn_s[i][j] = aij + upd;
    }
    attn_s[j][j] = 1.f;
  }
  __syncthreads();
  {
    const int r = tid >> 3, cg = (tid & 7) * 32;
    float ua[32], wa[32];
#pragma unroll
    for (int e = 0; e < 32; ++e) { ua[e] = 0.f; wa[e] = 0.f; }
    for (int j = 0; j < 32; ++j) {
      float a = attn_s[r][j];
#pragma unroll
      for (int e0 = 0; e0 < 32; e0 += 8) {
        us8 v8 = *(const us8*)&vbs[j][cg + e0];
        us8 k8 = *(const us8*)&kbs[j][cg + e0];
#pragma unroll
        for (int e = 0; e < 8; ++e) {
          ua[e0 + e] += a * bf2f(v8[e]);
          wa[e0 + e] += a * bf2f(k8[e]);
        }
      }
    }
    const size_t ob = ((size_t)bh * 4096 + l0 + r) * 256 + cg;
#pragma unroll
    for (int e0 = 0; e0 < 32; e0 += 8) {
      us8 pu, pw;
#pragma unroll
      for (int e = 0; e < 8; ++e) { pu[e] = f2bf(ua[e0 + e]); pw[e] = f2bf(wa[e0 + e]); }
      *(us8*)&ug[ob + e0] = pu;
      *(us8*)&wg[ob + e0] = pw;
    }
  }
}

// ---------- features_pre (STANDALONE, no LDS -> full occupancy):
// branches {0,1,2,4} stats + 6 crosses + hid copy + zero pad ----------
__global__ __launch_bounds__(256) void features_pre(const float* __restrict__ hid,
    const u16t* __restrict__ vc, const float* __restrict__ w3g,
    const float* __restrict__ w7g, const float* __restrict__ w25g,
    const float* __restrict__ w1g, u16t* __restrict__ router, float* __restrict__ s2buf) {
  const int m = blockIdx.x, tid = threadIdx.x;
  const int h = tid >> 6, l = tid & 63;
  const int b = m >> 12, lseq = m & 4095;
  const int c0 = h * 256 + l * 4;
  float xb[4][4];  // bidx: 0->br0(K3), 1->br1(K7), 2->br2(K25), 3->br4(K1)
  {
    float win[7][4];
    float x25[4] = {0.f, 0.f, 0.f, 0.f};
#pragma unroll
    for (int j = 0; j < 25; ++j) {
      float xv[4];
      int ls = lseq - 24 + j;
      if (ls >= 0) {
        us4 v = *(const us4*)&vc[((size_t)b * 4096 + ls) * 1024 + c0];
#pragma unroll
        for (int e = 0; e < 4; ++e) xv[e] = bf2f(v[e]);
      } else {
#pragma unroll
        for (int e = 0; e < 4; ++e) xv[e] = 0.f;
      }
#pragma unroll
      for (int e = 0; e < 4; ++e) x25[e] += xv[e] * w25g[(c0 + e) * 25 + j];
      if (j >= 18) {
#pragma unroll
        for (int e = 0; e < 4; ++e) win[j - 18][e] = xv[e];
      }
    }
#pragma unroll
    for (int e = 0; e < 4; ++e) {
      const int c = c0 + e;
      xb[0][e] = win[4][e] * w3g[c * 3] + win[5][e] * w3g[c * 3 + 1] +
                 win[6][e] * w3g[c * 3 + 2];
      float m_ = 0.f;
#pragma unroll
      for (int j = 0; j < 7; ++j) m_ += win[j][e] * w7g[c * 7 + j];
      xb[1][e] = m_;
      xb[2][e] = x25[e];
      xb[3][e] = win[6][e] * w1g[c];
    }
  }
  float s1[4], s2[4], mx[4], ent[4];
#pragma unroll
  for (int bi = 0; bi < 4; ++bi) {
    float a = 0.f, bq = 0.f, m_ = -1e30f;
#pragma unroll
    for (int e = 0; e < 4; ++e) {
      a += xb[bi][e]; bq += xb[bi][e] * xb[bi][e]; m_ = fmaxf(m_, xb[bi][e]);
    }
    s1[bi] = wsum(a); s2[bi] = wsum(bq); mx[bi] = wmax(m_);
    float ee[4], e_ = 0.f;
#pragma unroll
    for (int e = 0; e < 4; ++e) { ee[e] = expf(xb[bi][e] - mx[bi]); e_ += ee[e]; }
    float es = wsum(e_);
    float hn = 0.f;
#pragma unroll
    for (int e = 0; e < 4; ++e) {
      float pv = ee[e] / es;
      hn += pv * logf(pv + 1e-8f);
    }
    ent[bi] = -wsum(hn);
  }
  // 6 crosses among real branches {0,1,2,4}; reference pair indices:
  // (0,1)->0 (0,2)->1 (0,4)->3 (1,2)->4 (1,4)->6 (2,4)->8
  const int pidx[6] = {0, 1, 3, 4, 6, 8};
  const int pa_[6] = {0, 0, 0, 1, 1, 2};
  const int pb_[6] = {1, 2, 3, 2, 3, 3};
  float dts[6];
#pragma unroll
  for (int pi = 0; pi < 6; ++pi) {
    float d = 0.f;
#pragma unroll
    for (int e = 0; e < 4; ++e) d += xb[pa_[pi]][e] * xb[pb_[pi]][e];
    dts[pi] = wsum(d);
  }
  if (l == 0) {
    u16t* rp = router + (size_t)m * 1152 + 1024;
    const int slot[4] = {0, 1, 2, 4};
#pragma unroll
    for (int bi = 0; bi < 4; ++bi) {
      float mean = s1[bi] * (1.f / 256.f);
      float var = (s2[bi] - s1[bi] * s1[bi] * (1.f / 256.f)) * (1.f / 255.f);
      rp[slot[bi] * 16 + 0 + h] = f2bf(mean);
      rp[slot[bi] * 16 + 4 + h] = f2bf(var);
      rp[slot[bi] * 16 + 8 + h] = f2bf(mx[bi]);
      rp[slot[bi] * 16 + 12 + h] = f2bf(ent[bi]);
      s2buf[((size_t)m * 4 + h) * 4 + bi] = s2[bi];
    }
#pragma unroll
    for (int pi = 0; pi < 6; ++pi) {
      float den = sqrtf(s2[pa_[pi]]) * sqrtf(s2[pb_[pi]]) + 1e-8f;
      rp[80 + pidx[pi] * 4 + h] = f2bf(dts[pi] / den);
    }
  }
  {
    f4 hv = *(const f4*)&hid[(size_t)m * 1024 + tid * 4];
    us4 hv4;
#pragma unroll
    for (int e = 0; e < 4; ++e) hv4[e] = f2bf(hv[e]);
    *(us4*)&router[(size_t)m * 1152 + tid * 4] = hv4;
  }
  if (tid < 8) router[(size_t)m * 1152 + 1144 + tid] = 0;
}

// ---------- fused launch: 0-31 scan | 32-543 FIR-25 | 544-671 padW1 |
// 672-735 packWo  (r10-proven shadow budget: ~3 rounds on 224 idle CUs) ----------
__global__ __launch_bounds__(256, 1) void delta_scan(const u16t* __restrict__ qn,
    const u16t* __restrict__ kn, const u16t* __restrict__ ug, const u16t* __restrict__ wg,
    u16t* __restrict__ dout, const u16t* __restrict__ vc, const float* __restrict__ w25g,
    u16t* __restrict__ fl, const float* __restrict__ W1, u16t* __restrict__ W1p,
    const float* __restrict__ Wo, u16t* __restrict__ wob) {
  const int blk = blockIdx.x;
  const int tid = threadIdx.x;
  if (blk < 32) {  // ===== delta scan (r5-proven structure) =====
    const int bh = blk >> 2, vbidx = blk & 3;
    const int b = bh >> 2, h = bh & 3;
    const int c0 = vbidx * 64;
    const int wv = tid >> 6, l = tid & 63;
    const int lr = l & 15, kg8 = (l >> 4) * 8, rg4 = (l >> 4) * 4;

    __shared__ u16t qs[32][264], ks2[32][264], wss[32][264];
    __shared__ u16t kts[256][40];
    __shared__ u16t sbf[64][264];
    __shared__ u16t las[32][40];
    __shared__ u16t uts[64][40];

    {
      u16t* sp = &sbf[0][0];
      for (int i = tid; i < 64 * 264; i += 256) sp[i] = 0;
    }
    const f4 zf = {0.f, 0.f, 0.f, 0.f};
    f4 sacc[16];
#pragma unroll
    for (int d = 0; d < 16; ++d) sacc[d] = zf;
    __syncthreads();

    const u16t* qb = qn + (size_t)b * 4096 * 1024 + (size_t)h * 256;
    const u16t* knb = kn + (size_t)b * 4096 * 1024 + (size_t)h * 256;
    const u16t* ub = ug + (size_t)bh * 4096 * 256;
    const u16t* wb = wg + (size_t)bh * 4096 * 256;
    const int sr = tid >> 5, sd8 = (tid & 31) * 8;

    us8 pq[4], pk[4], pw[4];
    us4 pu0, pu1;
#pragma unroll
    for (int i = 0; i < 4; ++i) {
      const int r = i * 8 + sr;
      pq[i] = *(const us8*)(qb + (size_t)r * 1024 + sd8);
      pk[i] = *(const us8*)(knb + (size_t)r * 1024 + sd8);
      pw[i] = *(const us8*)(wb + (size_t)r * 256 + sd8);
    }
    pu0 = *(const us4*)(ub + (size_t)lr * 256 + c0 + wv * 16 + rg4);
    pu1 = *(const us4*)(ub + (size_t)(16 + lr) * 256 + c0 + wv * 16 + rg4);

    for (int ci = 0; ci < 128; ++ci) {
      const int l0 = ci * 32;
#pragma unroll
      for (int i = 0; i < 4; ++i) {
        const int r = i * 8 + sr;
        *(us8*)&qs[r][sd8] = pq[i];
        *(us8*)&ks2[r][sd8] = pk[i];
        *(us8*)&wss[r][sd8] = pw[i];
      }
      const us4 u0 = pu0, u1 = pu1;
      __syncthreads();
      if (ci < 127) {
        const int l1 = l0 + 32;
#pragma unroll
        for (int i = 0; i < 4; ++i) {
          const int r = i * 8 + sr;
          pq[i] = *(const us8*)(qb + (size_t)(l1 + r) * 1024 + sd8);
          pk[i] = *(const us8*)(knb + (size_t)(l1 + r) * 1024 + sd8);
          pw[i] = *(const us8*)(wb + (size_t)(l1 + r) * 256 + sd8);
        }
        pu0 = *(const us4*)(ub + (size_t)(l1 + lr) * 256 + c0 + wv * 16 + rg4);
        pu1 = *(const us4*)(ub + (size_t)(l1 + 16 + lr) * 256 + c0 + wv * 16 + rg4);
      }
      {
        const int dk = tid;
        const int swz = ((dk >> 3) & 3) << 3;
#pragma unroll
        for (int r = 0; r < 32; r += 2) {
          unsigned int lo = ks2[r][dk], hi = ks2[r + 1][dk];
          *(unsigned int*)&kts[dk][r ^ swz] = lo | (hi << 16);
        }
      }
      {
        const int rq = wv >> 1, rk = wv & 1;
        f4 t4 = zf;
#pragma unroll
        for (int ks = 0; ks < 8; ++ks) {
          bf8v a = *(const bf8v*)&qs[rq * 16 + lr][ks * 32 + kg8];
          bf8v bb = *(const bf8v*)&ks2[rk * 16 + lr][ks * 32 + kg8];
          t4 = MFMA(a, bb, t4);
        }
        const int colj = rk * 16 + lr;
#pragma unroll
        for (int rr = 0; rr < 4; ++rr) {
          const int rowr = rq * 16 + rg4 + rr;
          las[rowr][colj] = (colj <= rowr) ? f2bf(t4[rr]) : (u16t)0;
        }
      }
      f4 o0 = zf, o1 = zf;
      {
        f4 m0 = zf, m1 = zf;
#pragma unroll
        for (int ks = 0; ks < 8; ++ks) {
          bf8v a = *(const bf8v*)&sbf[wv * 16 + lr][ks * 32 + kg8];
          bf8v wb0 = *(const bf8v*)&wss[lr][ks * 32 + kg8];
          bf8v wb1 = *(const bf8v*)&wss[16 + lr][ks * 32 + kg8];
          bf8v qb0 = *(const bf8v*)&qs[lr][ks * 32 + kg8];
          bf8v qb1 = *(const bf8v*)&qs[16 + lr][ks * 32 + kg8];
          m0 = MFMA(a, wb0, m0);
          m1 = MFMA(a, wb1, m1);
          o0 = MFMA(a, qb0, o0);
          o1 = MFMA(a, qb1, o1);
        }
#pragma unroll
        for (int rt = 0; rt < 2; ++rt) {
          f4 mm = rt ? m1 : m0;
          const us4 uu = rt ? u1 : u0;
          const int r = rt * 16 + lr;
#pragma unroll
          for (int rr = 0; rr < 4; ++rr)
            uts[wv * 16 + rg4 + rr][r] = f2bf(bf2f(uu[rr]) - mm[rr]);
        }
      }
      __syncthreads();
      {
        bf8v a2 = *(const bf8v*)&uts[wv * 16 + lr][kg8];
        {
          bf8v lb0 = *(const bf8v*)&las[lr][kg8];
          bf8v lb1 = *(const bf8v*)&las[16 + lr][kg8];
          o0 = MFMA(a2, lb0, o0);
          o1 = MFMA(a2, lb1, o1);
        }
#pragma unroll
        for (int rt = 0; rt < 2; ++rt) {
          f4 oo = rt ? o1 : o0;
          const int r = rt * 16 + lr;
          us4 st;
#pragma unroll
          for (int rr = 0; rr < 4; ++rr) st[rr] = f2bf(oo[rr]);
          *(us4*)(dout + ((size_t)(b * 4096 + l0 + r) * 4 + h) * 256 + c0 + wv * 16 + rg4) = st;
        }
#pragma unroll
        for (int d = 0; d < 16; ++d) {
          const int swzd = ((2 * d + (lr >> 3)) & 3) << 3;
          bf8v bb = *(const bf8v*)&kts[d * 16 + lr][kg8 ^ swzd];
          sacc[d] = MFMA(a2, bb, sacc[d]);
        }
#pragma unroll
        for (int d = 0; d < 16; ++d) {
#pragma unroll
          for (int rr = 0; rr < 4; ++rr)
            sbf[wv * 16 + rg4 + rr][d * 16 + lr] = f2bf(sacc[d][rr]);
        }
      }
      __syncthreads();
    }
    return;
  }
  if (blk < 544) {  // ===== 25-tap FIR (fl branch, for mix/features_post) =====
    const int fb = blk - 32;
    const int l0 = (fb & 63) * 64;
    const int by = fb >> 6;
    const int b = by >> 2, cb = by & 3;
    const int c = cb * 256 + tid;
    __shared__ u16t sm[88][256];
    for (int i = 0; i < 88; ++i) {
      int ls = l0 - 24 + i;
      sm[i][tid] = (ls >= 0) ? vc[((size_t)b * 4096 + ls) * 1024 + c] : (u16t)0;
    }
    __syncthreads();
    float w25[25];
#pragma unroll
    for (int j = 0; j < 25; ++j) w25[j] = w25g[c * 25 + j];
    float x[25];
#pragma unroll
    for (int j = 0; j < 25; ++j) x[j] = bf2f(sm[j][tid]);
    for (int ll = 0; ll < 64; ++ll) {
      float yl = 0.f;
#pragma unroll
      for (int j = 0; j < 25; ++j) yl += x[j] * w25[j];
      fl[((size_t)b * 4096 + l0 + ll) * 1024 + c] = f2bf(yl);
      if (ll < 63) {
#pragma unroll
        for (int j = 0; j < 24; ++j) x[j] = x[j + 1];
        x[24] = bf2f(sm[ll + 25][tid]);
      }
    }
    return;
  }
  if (blk < 672) {  // ===== pad W1 f32->bf16 =====
    for (size_t idx = (size_t)(blk - 544) * 256 + tid; idx < (size_t)2304 * 1152;
         idx += (size_t)128 * 256) {
      int n = (int)(idx / 1152), k = (int)(idx % 1152);
      W1p[idx] = (n < 2288 && k < 1144) ? f2bf(W1[(size_t)n * 1144 + k]) : (u16t)0;
    }
    return;
  }
  // ===== pack Wo f32->bf16 =====
  for (size_t i = (size_t)(blk - 672) * 256 + tid; i < 262144; i += (size_t)64 * 256) {
    f4 v = *(const f4*)&Wo[i * 4];
    us4 o;
#pragma unroll
    for (int e = 0; e < 4; ++e) o[e] = f2bf(v[e]);
    *(us4*)&wob[i * 4] = o;
  }
}

// ---------- on-the-fly small FIR branches (K=3,7,1) from vc ----------
__device__ __forceinline__ void fir_otf(const u16t* __restrict__ vc,
    const float* __restrict__ w3g, const float* __restrict__ w7g,
    const float* __restrict__ w1g, int b, int lseq, int c0,
    float ys[4], float ym[4], float yi[4]) {
  float xs[7][4];
#pragma unroll
  for (int j = 0; j < 7; ++j) {
    int ls = lseq - 6 + j;
    if (ls >= 0) {
      us4 v = *(const us4*)&vc[((size_t)b * 4096 + ls) * 1024 + c0];
#pragma unroll
      for (int e = 0; e < 4; ++e) xs[j][e] = bf2f(v[e]);
    } else {
#pragma unroll
      for (int e = 0; e < 4; ++e) xs[j][e] = 0.f;
    }
  }
#pragma unroll
  for (int e = 0; e < 4; ++e) {
    const int c = c0 + e;
    ys[e] = xs[4][e] * w3g[c * 3] + xs[5][e] * w3g[c * 3 + 1] + xs[6][e] * w3g[c * 3 + 2];
    float m_ = 0.f;
#pragma unroll
    for (int j = 0; j < 7; ++j) m_ += xs[j][e] * w7g[c * 7 + j];
    ym[e] = m_;
    yi[e] = xs[6][e] * w1g[c];
  }
}

// ---------- features_post: branch-3 (delta) stats + 4 delta crosses ----------
__global__ __launch_bounds__(256) void features_post(const u16t* __restrict__ vc,
    const float* __restrict__ w3g, const float* __restrict__ w7g,
    const float* __restrict__ w1g, const u16t* __restrict__ fl,
    const u16t* __restrict__ dlt, const float* __restrict__ s2buf,
    u16t* __restrict__ router) {
  const int m = blockIdx.x, tid = threadIdx.x;
  const int h = tid >> 6, l = tid & 63;
  const int b = m >> 12, lseq = m & 4095;
  const int c0 = h * 256 + l * 4;
  const size_t base = (size_t)m * 1024 + c0;
  float x0[4], x1[4], x4[4], x2[4], x3[4];
  fir_otf(vc, w3g, w7g, w1g, b, lseq, c0, x0, x1, x4);
  {
    us4 v2 = *(const us4*)&fl[base];
    us4 v3 = *(const us4*)&dlt[base];
#pragma unroll
    for (int e = 0; e < 4; ++e) { x2[e] = bf2f(v2[e]); x3[e] = bf2f(v3[e]); }
  }
  float a = 0.f, bq = 0.f, m_ = -1e30f;
#pragma unroll
  for (int e = 0; e < 4; ++e) { a += x3[e]; bq += x3[e] * x3[e]; m_ = fmaxf(m_, x3[e]); }
  float s1_3 = wsum(a), s2_3 = wsum(bq), mx3 = wmax(m_);
  float ee[4], e_ = 0.f;
#pragma unroll
  for (int e = 0; e < 4; ++e) { ee[e] = expf(x3[e] - mx3); e_ += ee[e]; }
  float es = wsum(e_);
  float hn = 0.f;
#pragma unroll
  for (int e = 0; e < 4; ++e) {
    float pv = ee[e] / es;
    hn += pv * logf(pv + 1e-8f);
  }
  float ent3 = -wsum(hn);
  float d03 = 0.f, d13 = 0.f, d23 = 0.f, d34 = 0.f;
#pragma unroll
  for (int e = 0; e < 4; ++e) {
    d03 += x0[e] * x3[e]; d13 += x1[e] * x3[e];
    d23 += x2[e] * x3[e]; d34 += x3[e] * x4[e];
  }
  d03 = wsum(d03); d13 = wsum(d13); d23 = wsum(d23); d34 = wsum(d34);
  if (l == 0) {
    u16t* rp = router + (size_t)m * 1152 + 1024;
    float mean = s1_3 * (1.f / 256.f);
    float var = (s2_3 - s1_3 * s1_3 * (1.f / 256.f)) * (1.f / 255.f);
    rp[3 * 16 + 0 + h] = f2bf(mean);
    rp[3 * 16 + 4 + h] = f2bf(var);
    rp[3 * 16 + 8 + h] = f2bf(mx3);
    rp[3 * 16 + 12 + h] = f2bf(ent3);
    const float* sb = &s2buf[((size_t)m * 4 + h) * 4];
    float r3 = sqrtf(s2_3);
    rp[80 + 2 * 4 + h] = f2bf(d03 / (sqrtf(sb[0]) * r3 + 1e-8f));
    rp[80 + 5 * 4 + h] = f2bf(d13 / (sqrtf(sb[1]) * r3 + 1e-8f));
    rp[80 + 7 * 4 + h] = f2bf(d23 / (sqrtf(sb[2]) * r3 + 1e-8f));
    rp[80 + 9 * 4 + h] = f2bf(d34 / (r3 * sqrtf(sb[3]) + 1e-8f));
  }
}

// ---------- fused W2 logits + softmax + floor + mix + RMSNorm ----------
__global__ __launch_bounds__(256) void route_mix(const u16t* __restrict__ hrt,
    const float* __restrict__ W2, const float* __restrict__ b2,
    const u16t* __restrict__ vc, const float* __restrict__ w3g,
    const float* __restrict__ w7g, const float* __restrict__ w1g,
    const u16t* __restrict__ fl, const u16t* __restrict__ dlt,
    const float* __restrict__ normw, u16t* __restrict__ mixed) {
  const int m = blockIdx.x, tid = threadIdx.x;
  const int h = tid >> 6, l = tid & 63;
  float acc[5];
#pragma unroll
  for (int n = 0; n < 5; ++n) acc[n] = 0.f;
  for (int kk = l * 4; kk < 2288; kk += 256) {
    us4 hv = *(const us4*)&hrt[(size_t)m * 2304 + kk];
    float hf[4];
#pragma unroll
    for (int e = 0; e < 4; ++e) hf[e] = bf2f(hv[e]);
#pragma unroll
    for (int n = 0; n < 5; ++n) {
      f4 wv4 = *(const f4*)&W2[(size_t)(h * 5 + n) * 2288 + kk];
#pragma unroll
      for (int e = 0; e < 4; ++e) acc[n] += hf[e] * wv4[e];
    }
  }
  float p5[5];
  {
    float lg[5];
#pragma unroll
    for (int n = 0; n < 5; ++n) lg[n] = wsum(acc[n]) + b2[h * 5 + n];
    float mxv = lg[0];
#pragma unroll
    for (int n = 1; n < 5; ++n) mxv = fmaxf(mxv, lg[n]);
    float es = 0.f, ev[5];
#pragma unroll
    for (int n = 0; n < 5; ++n) { ev[n] = expf(lg[n] - mxv); es += ev[n]; }
#pragma unroll
    for (int n = 0; n < 5; ++n) p5[n] = (ev[n] / es) * 0.95f + 0.01f;
  }
  const int b = m >> 12, lseq = m & 4095;
  const int c0 = h * 256 + l * 4;
  const size_t base = (size_t)m * 1024 + c0;
  float x[5][4];
  fir_otf(vc, w3g, w7g, w1g, b, lseq, c0, x[0], x[1], x[4]);
  {
    us4 v2 = *(const us4*)&fl[base];
    us4 v3 = *(const us4*)&dlt[base];
#pragma unroll
    for (int e = 0; e < 4; ++e) { x[2][e] = bf2f(v2[e]); x[3][e] = bf2f(v3[e]); }
  }
  float o[4] = {0.f, 0.f, 0.f, 0.f};
#pragma unroll
  for (int br = 0; br < 5; ++br)
#pragma unroll
    for (int e = 0; e < 4; ++e) o[e] += p5[br] * x[br][e];
  float ss = 0.f;
#pragma unroll
  for (int e = 0; e < 4; ++e) ss += o[e] * o[e];
  ss = wsum(ss);
  float sc = rsqrtf(ss * (1.f / 256.f) + 1e-5f);
  f4 nw = *(const f4*)&normw[l * 4];
  us4 ov;
#pragma unroll
  for (int e = 0; e < 4; ++e) ov[e] = f2bf(o[e] * sc * nw[e]);
  *(us4*)&mixed[base] = ov;
}

// ---------- launcher ----------
extern "C" void kernel_launch(void* const* d_in, const int* in_sizes, int n_in,
                              void* d_out, int out_size, void* d_ws, size_t ws_size,
                              hipStream_t stream) {
  (void)in_sizes; (void)n_in; (void)out_size; (void)ws_size;
  const float* hid = (const float*)d_in[0];
  const float* Wq = (const float*)d_in[1];
  const float* Wk = (const float*)d_in[2];
  const float* Wv = (const float*)d_in[3];
  const float* wqc = (const float*)d_in[4];
  const float* wkc = (const float*)d_in[5];
  const float* wvc = (const float*)d_in[6];
  const float* Wb = (const float*)d_in[7];
  const float* fsw = (const float*)d_in[8];
  const float* fmw = (const float*)d_in[9];
  const float* flw = (const float*)d_in[10];
  const float* fiw = (const float*)d_in[11];
  const float* W1 = (const float*)d_in[12];
  const float* b1 = (const float*)d_in[13];
  const float* W2 = (const float*)d_in[14];
  const float* b2 = (const float*)d_in[15];
  const float* nwt = (const float*)d_in[16];
  const float* Wo = (const float*)d_in[17];
  float* out = (float*)d_out;

  char* wsp = (char*)d_ws;
  const size_t S = (size_t)2 * 4096 * 1024 * 2;  // 16 MiB per (B,L,D) bf16 buffer
  u16t* ql = (u16t*)(wsp + 0 * S);
  u16t* kl = (u16t*)(wsp + 1 * S);
  u16t* vl = (u16t*)(wsp + 2 * S);
  u16t* qc = (u16t*)(wsp + 3 * S);
  u16t* kc = (u16t*)(wsp + 4 * S);
  u16t* vc = (u16t*)(wsp + 5 * S);
  u16t* ubuf = (u16t*)(wsp + 6 * S);
  u16t* wbuf = (u16t*)(wsp + 7 * S);
  char* p = wsp + 8 * S;
  u16t* router = (u16t*)p; p += (size_t)8192 * 1152 * 2;
  u16t* hrt = (u16t*)p;    p += (size_t)8192 * 2304 * 2;
  u16t* w1p = (u16t*)p;    p += (size_t)2304 * 1152 * 2;
  u16t* wob = (u16t*)p;    p += (size_t)1024 * 1024 * 2;
  float* s2buf = (float*)p; p += (size_t)8192 * 4 * 4 * 4;
  // buffer reuse (lifetime-checked):
  u16t* hidb = qc;          // dead before conv writes qc
  u16t* wqb = kc;           // dead before conv writes kc
  u16t* wkb = kc + 1048576;
  u16t* wvb = kc + 2097152;
  u16t* kbeta = ql;   // ql dead after conv; kbeta dead after chunk_uw
  u16t* vbeta = kl;   // kl dead after conv; vbeta dead after chunk_uw
  u16t* dlt = kl;     // scan output
  u16t* f_l = vl;     // vl dead after conv; written by scan-shadow FIR
  u16t* mixed = wbuf; // wbuf (wg) dead after scan

  dim3 blk(256);
  pack_all<<<dim3(11264), blk, 0, stream>>>(hid, Wq, Wk, Wv, hidb, wqb, wkb, wvb);
  gemm_qkv3<<<dim3(8, 64, 3), blk, 0, stream>>>(hidb, wqb, wkb, wvb, ql, kl, vl);
  conv4_silu<<<dim3(64, 8, 3), blk, 0, stream>>>(ql, kl, vl, wqc, wkc, wvc, qc, kc, vc);
  prep_kernel<<<dim3(8192), blk, 0, stream>>>(qc, kc, vc, hid, Wb, kbeta, vbeta);
  chunk_uw<<<dim3(1024), blk, 0, stream>>>(kc, kbeta, vbeta, ubuf, wbuf);
  features_pre<<<dim3(8192), blk, 0, stream>>>(hid, vc, fsw, fmw, flw, fiw, router, s2buf);
  delta_scan<<<dim3(736), blk, 0, stream>>>(qc, kc, ubuf, wbuf, dlt, vc, flw, f_l,
                                            W1, w1p, Wo, wob);
  features_post<<<dim3(8192), blk, 0, stream>>>(vc, fsw, fmw, fiw, f_l, dlt, s2buf, router);
  gemm_bt<false, 1><<<dim3(18, 64), blk, 0, stream>>>(router, w1p, hrt, b1, 1152, 1152, 1152, 2304);
  route_mix<<<dim3(8192), blk, 0, stream>>>(hrt, W2, b2, vc, fsw, fmw, fiw, f_l, dlt, nwt, mixed);
  gemm_bt<true, 0><<<dim3(8, 64), blk, 0, stream>>>(mixed, wob, out, nullptr, 1024, 1024, 1024, 1024);
}

// Round 13
// 1039.108 us; speedup vs baseline: 1.5445x; 1.5445x over previous
//
#include <hip/hip_runtime.h>
#include <stdint.h>

// ---------- types / helpers ----------
typedef unsigned short u16t;
typedef u16t us4 __attribute__((ext_vector_type(4)));
typedef u16t us8 __attribute__((ext_vector_type(8)));
typedef __bf16 bf8v __attribute__((ext_vector_type(8)));
typedef float f4 __attribute__((ext_vector_type(4)));

#define MFMA(a, b, c) __builtin_amdgcn_mfma_f32_16x16x32_bf16((a), (b), (c), 0, 0, 0)
#define GLOAD_LDS16(g, l) __builtin_amdgcn_global_load_lds( \
    (const __attribute__((address_space(1))) void*)(g),     \
    (__attribute__((address_space(3))) void*)(l), 16, 0, 0)

__device__ __forceinline__ float bf2f(u16t u) {
  union { unsigned int i; float f; } c; c.i = ((unsigned int)u) << 16; return c.f;
}
__device__ __forceinline__ u16t f2bf(float f) {
  union { float f; unsigned int i; } c; c.f = f;
  return (u16t)((c.i + 0x7FFFu + ((c.i >> 16) & 1u)) >> 16);
}
__device__ __forceinline__ float wsum(float v) {
#pragma unroll
  for (int o = 32; o > 0; o >>= 1) v += __shfl_xor(v, o);
  return v;
}
__device__ __forceinline__ float wmax(float v) {
#pragma unroll
  for (int o = 32; o > 0; o >>= 1) v = fmaxf(v, __shfl_xor(v, o));
  return v;
}

// ---------- pack hid+Wq+Wk+Wv f32->bf16 in one launch ----------
__global__ __launch_bounds__(256) void pack_all(const float* __restrict__ hid,
    const float* __restrict__ Wq, const float* __restrict__ Wk, const float* __restrict__ Wv,
    u16t* __restrict__ hidb, u16t* __restrict__ wqb, u16t* __restrict__ wkb,
    u16t* __restrict__ wvb) {
  const int g = blockIdx.x * 256 + threadIdx.x;  // grid covers 2883584 groups
  const float* src; u16t* dst; int off;
  if (g < 2097152) { src = hid; dst = hidb; off = g; }
  else if (g < 2359296) { src = Wq; dst = wqb; off = g - 2097152; }
  else if (g < 2621440) { src = Wk; dst = wkb; off = g - 2359296; }
  else { src = Wv; dst = wvb; off = g - 2621440; }
  f4 v = *(const f4*)&src[(size_t)off * 4];
  us4 o;
#pragma unroll
  for (int e = 0; e < 4; ++e) o[e] = f2bf(v[e]);
  *(us4*)&dst[(size_t)off * 4] = o;
}

// ---------- GEMM (all-bf16 operands): C[M,N] = A[M,K] @ Bt[N,K]^T ----------
// global_load_lds width=16 staging. LDS LINEAR [128][32]. EPI==1: bias+GELU.
template <bool CF32, int EPI>
__device__ __forceinline__ void gemm_body(const u16t* __restrict__ A,
    const u16t* __restrict__ Bt, void* __restrict__ Cv, const float* __restrict__ bias,
    int K, int lda, int ldb, int ldc, int m0, int n0) {
  __shared__ u16t As[128][32];
  __shared__ u16t Bs[128][32];
  const int tid = threadIdx.x;
  const int wv = tid >> 6, l = tid & 63;
  const int wr = wv >> 1, wc = wv & 1;
  const int lr = l & 15, kg8 = (l >> 4) * 8, rg4 = (l >> 4) * 4;
  const f4 zf = {0.f, 0.f, 0.f, 0.f};
  f4 acc[4][4];
#pragma unroll
  for (int i = 0; i < 4; ++i)
#pragma unroll
    for (int j = 0; j < 4; ++j) acc[i][j] = zf;

  const u16t* ga = A + (size_t)(m0 + wv * 32 + (l >> 2)) * lda + (l & 3) * 8;
  const u16t* gb = Bt + (size_t)(n0 + wv * 32 + (l >> 2)) * ldb + (l & 3) * 8;
  u16t* la0 = &As[wv * 32][0];
  u16t* la1 = &As[wv * 32 + 16][0];
  u16t* lb0 = &Bs[wv * 32][0];
  u16t* lb1 = &Bs[wv * 32 + 16][0];

  for (int kt = 0; kt < K; kt += 32) {
    GLOAD_LDS16(ga + kt, la0);
    GLOAD_LDS16(ga + (size_t)16 * lda + kt, la1);
    GLOAD_LDS16(gb + kt, lb0);
    GLOAD_LDS16(gb + (size_t)16 * ldb + kt, lb1);
    __syncthreads();
    bf8v af[4], bg[4];
#pragma unroll
    for (int f = 0; f < 4; ++f) af[f] = *(const bf8v*)&As[wr * 64 + f * 16 + lr][kg8];
#pragma unroll
    for (int f = 0; f < 4; ++f) bg[f] = *(const bf8v*)&Bs[wc * 64 + f * 16 + lr][kg8];
#pragma unroll
    for (int i = 0; i < 4; ++i)
#pragma unroll
      for (int j = 0; j < 4; ++j) acc[i][j] = MFMA(af[i], bg[j], acc[i][j]);
    __syncthreads();
  }
#pragma unroll
  for (int i = 0; i < 4; ++i) {
    const int rb = m0 + wr * 64 + i * 16 + rg4;
#pragma unroll
    for (int j = 0; j < 4; ++j) {
      const int cb = n0 + wc * 64 + j * 16 + lr;
#pragma unroll
      for (int r = 0; r < 4; ++r) {
        float x = acc[i][j][r];
        if (EPI == 1) {
          float xx = x + ((cb < 2288) ? bias[cb] : 0.f);
          x = 0.5f * xx * (1.f + erff(xx * 0.70710678118f));
        }
        if (CF32)
          ((float*)Cv)[(size_t)(rb + r) * ldc + cb] = x;
        else
          ((u16t*)Cv)[(size_t)(rb + r) * ldc + cb] = f2bf(x);
      }
    }
  }
}

template <bool CF32, int EPI>
__global__ __launch_bounds__(256) void gemm_bt(const u16t* __restrict__ Av,
    const u16t* __restrict__ Btv, void* __restrict__ Cv, const float* __restrict__ bias,
    int K, int lda, int ldb, int ldc) {
  gemm_body<CF32, EPI>(Av, Btv, Cv, bias, K, lda, ldb, ldc,
                       blockIdx.y * 128, blockIdx.x * 128);
}

__global__ __launch_bounds__(256) void gemm_qkv3(const u16t* __restrict__ A,
    const u16t* __restrict__ B0, const u16t* __restrict__ B1,
    const u16t* __restrict__ B2, u16t* __restrict__ C0, u16t* __restrict__ C1,
    u16t* __restrict__ C2v) {
  const int z = blockIdx.z;
  const u16t* Bt = (z == 0) ? B0 : ((z == 1) ? B1 : B2);
  u16t* C = (z == 0) ? C0 : ((z == 1) ? C1 : C2v);
  gemm_body<false, 0>(A, Bt, C, nullptr, 1024, 1024, 1024, 1024,
                      blockIdx.y * 128, blockIdx.x * 128);
}

// ---------- depthwise causal conv K=4 + SiLU (sliding-window registers) ----------
__global__ __launch_bounds__(256) void conv4_silu(
    const u16t* __restrict__ qlin, const u16t* __restrict__ klin, const u16t* __restrict__ vlin,
    const float* __restrict__ wq, const float* __restrict__ wk, const float* __restrict__ wvv,
    u16t* __restrict__ qc, u16t* __restrict__ kc, u16t* __restrict__ vc) {
  const int tid = threadIdx.x;
  const int l0 = blockIdx.x * 64;
  const int b = blockIdx.y >> 2, cb = blockIdx.y & 3;
  const int z = blockIdx.z;
  const u16t* in_ = (z == 0) ? qlin : ((z == 1) ? klin : vlin);
  const float* w_ = (z == 0) ? wq : ((z == 1) ? wk : wvv);
  u16t* out_ = (z == 0) ? qc : ((z == 1) ? kc : vc);
  const int c = cb * 256 + tid;
  __shared__ u16t sm[67][256];
  for (int i = 0; i < 67; ++i) {
    int ls = l0 - 3 + i;
    sm[i][tid] = (ls >= 0) ? in_[((size_t)b * 4096 + ls) * 1024 + c] : (u16t)0;
  }
  __syncthreads();
  f4 w4 = *(const f4*)&w_[c * 4];
  float x0 = bf2f(sm[0][tid]), x1 = bf2f(sm[1][tid]), x2 = bf2f(sm[2][tid]);
  for (int ll = 0; ll < 64; ++ll) {
    float x3 = bf2f(sm[ll + 3][tid]);
    float y = x0 * w4[0] + x1 * w4[1] + x2 * w4[2] + x3 * w4[3];
    y = y / (1.f + expf(-y));
    out_[((size_t)b * 4096 + l0 + ll) * 1024 + c] = f2bf(y);
    x0 = x1; x1 = x2; x2 = x3;
  }
}

// ---------- fused beta + l2norm(q,k) + kb/vb ----------
__global__ __launch_bounds__(256) void prep_kernel(u16t* __restrict__ qc, u16t* __restrict__ kc,
    const u16t* __restrict__ vc, const float* __restrict__ hid, const float* __restrict__ Wb,
    u16t* __restrict__ kbeta, u16t* __restrict__ vbeta) {
  const int m = blockIdx.x, tid = threadIdx.x;
  const int h = tid >> 6, l = tid & 63;
  float bacc = 0.f;
#pragma unroll
  for (int it = 0; it < 4; ++it) {
    int kk = l * 4 + it * 256;
    f4 hv = *(const f4*)&hid[(size_t)m * 1024 + kk];
    f4 wv4 = *(const f4*)&Wb[(size_t)h * 1024 + kk];
#pragma unroll
    for (int e = 0; e < 4; ++e) bacc += hv[e] * wv4[e];
  }
  const float bet = 1.f / (1.f + expf(-wsum(bacc)));
  const size_t base = (size_t)m * 1024 + h * 256 + l * 4;
  us4 q4 = *(const us4*)&qc[base];
  float qf[4]; float ss = 0.f;
#pragma unroll
  for (int e = 0; e < 4; ++e) { qf[e] = bf2f(q4[e]); ss += qf[e] * qf[e]; }
  float qsc = rsqrtf(wsum(ss) + 1e-12f);
  us4 qo;
#pragma unroll
  for (int e = 0; e < 4; ++e) qo[e] = f2bf(qf[e] * qsc);
  *(us4*)&qc[base] = qo;
  us4 k4 = *(const us4*)&kc[base];
  float kf[4]; ss = 0.f;
#pragma unroll
  for (int e = 0; e < 4; ++e) { kf[e] = bf2f(k4[e]); ss += kf[e] * kf[e]; }
  float ksc = rsqrtf(wsum(ss) + 1e-12f);
  us4 ko, kbo;
#pragma unroll
  for (int e = 0; e < 4; ++e) {
    float kn = kf[e] * ksc;
    ko[e] = f2bf(kn);
    kbo[e] = f2bf(kn * bet);
  }
  *(us4*)&kc[base] = ko;
  *(us4*)&kbeta[base] = kbo;
  us4 v4 = *(const us4*)&vc[base];
  us4 vo;
#pragma unroll
  for (int e = 0; e < 4; ++e) vo[e] = f2bf(bf2f(v4[e]) * bet);
  *(us4*)&vbeta[base] = vo;
}

// ---------- per-chunk triangular inverse, u = T@vb, w = T@kb (MFMA phase 1) ----------
__global__ __launch_bounds__(256) void chunk_uw(const u16t* __restrict__ kn,
    const u16t* __restrict__ kbeta, const u16t* __restrict__ vbeta,
    u16t* __restrict__ ug, u16t* __restrict__ wg) {
  const int tid = threadIdx.x;
  const int bh = blockIdx.x >> 7, ci = blockIdx.x & 127;
  const int b = bh >> 2, h = bh & 3;
  const int l0 = ci * 32;
  __shared__ u16t kns[32][264], kbs[32][264], vbs[32][264];
  __shared__ float attn_s[32][33];
  const int sr = tid >> 5, sd8 = (tid & 31) * 8;
  const size_t rowbase = (size_t)b * 4096 * 1024 + (size_t)h * 256;
#pragma unroll
  for (int i = 0; i < 4; ++i) {
    int r = i * 8 + sr;
    size_t g = rowbase + (size_t)(l0 + r) * 1024 + sd8;
    *(us8*)&kns[r][sd8] = *(const us8*)&kn[g];
    *(us8*)&kbs[r][sd8] = *(const us8*)&kbeta[g];
    *(us8*)&vbs[r][sd8] = *(const us8*)&vbeta[g];
  }
  __syncthreads();
  {  // phase 1 via MFMA: wave wv -> 16x16 tile (rq, rk)
    const int wv = tid >> 6, l = tid & 63;
    const int lr = l & 15, kg8 = (l >> 4) * 8, rg4 = (l >> 4) * 4;
    const int rq = wv >> 1, rk = wv & 1;
    f4 t4 = {0.f, 0.f, 0.f, 0.f};
#pragma unroll
    for (int ks = 0; ks < 8; ++ks) {
      bf8v a = *(const bf8v*)&kbs[rq * 16 + lr][ks * 32 + kg8];
      bf8v bb = *(const bf8v*)&kns[rk * 16 + lr][ks * 32 + kg8];
      t4 = MFMA(a, bb, t4);
    }
    const int colj = rk * 16 + lr;
#pragma unroll
    for (int rr = 0; rr < 4; ++rr) {
      const int rowr = rq * 16 + rg4 + rr;
      attn_s[rowr][colj] = (colj < rowr) ? -t4[rr] : 0.f;
    }
  }
  __syncthreads();
  if (tid < 32) {
    const int j = tid;
    for (int i = 1; i < 32; ++i) {
      float aij = attn_s[i][j];
      float upd = 0.f;
#pragma unroll 1
      for (int k = 1; k < 31; ++k) {
        float aik = __shfl(aij, k);
        float akj = (k > j && k < i) ? attn_s[k][j] : 0.f;
        upd += aik * akj;
      }
      if (j < i) attn_s[i][j] = aij + upd;
    }
    attn_s[j][j] = 1.f;
  }
  __syncthreads();
  {
    const int r = tid >> 3, cg = (tid & 7) * 32;
    float ua[32], wa[32];
#pragma unroll
    for (int e = 0; e < 32; ++e) { ua[e] = 0.f; wa[e] = 0.f; }
    for (int j = 0; j < 32; ++j) {
      float a = attn_s[r][j];
#pragma unroll
      for (int e0 = 0; e0 < 32; e0 += 8) {
        us8 v8 = *(const us8*)&vbs[j][cg + e0];
        us8 k8 = *(const us8*)&kbs[j][cg + e0];
#pragma unroll
        for (int e = 0; e < 8; ++e) {
          ua[e0 + e] += a * bf2f(v8[e]);
          wa[e0 + e] += a * bf2f(k8[e]);
        }
      }
    }
    const size_t ob = ((size_t)bh * 4096 + l0 + r) * 256 + cg;
#pragma unroll
    for (int e0 = 0; e0 < 32; e0 += 8) {
      us8 pu, pw;
#pragma unroll
      for (int e = 0; e < 8; ++e) { pu[e] = f2bf(ua[e0 + e]); pw[e] = f2bf(wa[e0 + e]); }
      *(us8*)&ug[ob + e0] = pu;
      *(us8*)&wg[ob + e0] = pw;
    }
  }
}

// ---------- fused launch: 0-31 scan | 32-543 FIR-25 | 544-671 padW1 |
// 672-735 packWo  (r10-proven shadow budget) ----------
__global__ __launch_bounds__(256, 1) void delta_scan(const u16t* __restrict__ qn,
    const u16t* __restrict__ kn, const u16t* __restrict__ ug, const u16t* __restrict__ wg,
    u16t* __restrict__ dout, const u16t* __restrict__ vc, const float* __restrict__ w25g,
    u16t* __restrict__ fl, const float* __restrict__ W1, u16t* __restrict__ W1p,
    const float* __restrict__ Wo, u16t* __restrict__ wob) {
  const int blk = blockIdx.x;
  const int tid = threadIdx.x;
  if (blk < 32) {  // ===== delta scan (r5-proven structure) =====
    const int bh = blk >> 2, vbidx = blk & 3;
    const int b = bh >> 2, h = bh & 3;
    const int c0 = vbidx * 64;
    const int wv = tid >> 6, l = tid & 63;
    const int lr = l & 15, kg8 = (l >> 4) * 8, rg4 = (l >> 4) * 4;

    __shared__ u16t qs[32][264], ks2[32][264], wss[32][264];
    __shared__ u16t kts[256][40];
    __shared__ u16t sbf[64][264];
    __shared__ u16t las[32][40];
    __shared__ u16t uts[64][40];

    {
      u16t* sp = &sbf[0][0];
      for (int i = tid; i < 64 * 264; i += 256) sp[i] = 0;
    }
    const f4 zf = {0.f, 0.f, 0.f, 0.f};
    f4 sacc[16];
#pragma unroll
    for (int d = 0; d < 16; ++d) sacc[d] = zf;
    __syncthreads();

    const u16t* qb = qn + (size_t)b * 4096 * 1024 + (size_t)h * 256;
    const u16t* knb = kn + (size_t)b * 4096 * 1024 + (size_t)h * 256;
    const u16t* ub = ug + (size_t)bh * 4096 * 256;
    const u16t* wb = wg + (size_t)bh * 4096 * 256;
    const int sr = tid >> 5, sd8 = (tid & 31) * 8;

    us8 pq[4], pk[4], pw[4];
    us4 pu0, pu1;
#pragma unroll
    for (int i = 0; i < 4; ++i) {
      const int r = i * 8 + sr;
      pq[i] = *(const us8*)(qb + (size_t)r * 1024 + sd8);
      pk[i] = *(const us8*)(knb + (size_t)r * 1024 + sd8);
      pw[i] = *(const us8*)(wb + (size_t)r * 256 + sd8);
    }
    pu0 = *(const us4*)(ub + (size_t)lr * 256 + c0 + wv * 16 + rg4);
    pu1 = *(const us4*)(ub + (size_t)(16 + lr) * 256 + c0 + wv * 16 + rg4);

    for (int ci = 0; ci < 128; ++ci) {
      const int l0 = ci * 32;
#pragma unroll
      for (int i = 0; i < 4; ++i) {
        const int r = i * 8 + sr;
        *(us8*)&qs[r][sd8] = pq[i];
        *(us8*)&ks2[r][sd8] = pk[i];
        *(us8*)&wss[r][sd8] = pw[i];
      }
      const us4 u0 = pu0, u1 = pu1;
      __syncthreads();
      if (ci < 127) {
        const int l1 = l0 + 32;
#pragma unroll
        for (int i = 0; i < 4; ++i) {
          const int r = i * 8 + sr;
          pq[i] = *(const us8*)(qb + (size_t)(l1 + r) * 1024 + sd8);
          pk[i] = *(const us8*)(knb + (size_t)(l1 + r) * 1024 + sd8);
          pw[i] = *(const us8*)(wb + (size_t)(l1 + r) * 256 + sd8);
        }
        pu0 = *(const us4*)(ub + (size_t)(l1 + lr) * 256 + c0 + wv * 16 + rg4);
        pu1 = *(const us4*)(ub + (size_t)(l1 + 16 + lr) * 256 + c0 + wv * 16 + rg4);
      }
      {
        const int dk = tid;
        const int swz = ((dk >> 3) & 3) << 3;
#pragma unroll
        for (int r = 0; r < 32; r += 2) {
          unsigned int lo = ks2[r][dk], hi = ks2[r + 1][dk];
          *(unsigned int*)&kts[dk][r ^ swz] = lo | (hi << 16);
        }
      }
      {
        const int rq = wv >> 1, rk = wv & 1;
        f4 t4 = zf;
#pragma unroll
        for (int ks = 0; ks < 8; ++ks) {
          bf8v a = *(const bf8v*)&qs[rq * 16 + lr][ks * 32 + kg8];
          bf8v bb = *(const bf8v*)&ks2[rk * 16 + lr][ks * 32 + kg8];
          t4 = MFMA(a, bb, t4);
        }
        const int colj = rk * 16 + lr;
#pragma unroll
        for (int rr = 0; rr < 4; ++rr) {
          const int rowr = rq * 16 + rg4 + rr;
          las[rowr][colj] = (colj <= rowr) ? f2bf(t4[rr]) : (u16t)0;
        }
      }
      f4 o0 = zf, o1 = zf;
      {
        f4 m0 = zf, m1 = zf;
#pragma unroll
        for (int ks = 0; ks < 8; ++ks) {
          bf8v a = *(const bf8v*)&sbf[wv * 16 + lr][ks * 32 + kg8];
          bf8v wb0 = *(const bf8v*)&wss[lr][ks * 32 + kg8];
          bf8v wb1 = *(const bf8v*)&wss[16 + lr][ks * 32 + kg8];
          bf8v qb0 = *(const bf8v*)&qs[lr][ks * 32 + kg8];
          bf8v qb1 = *(const bf8v*)&qs[16 + lr][ks * 32 + kg8];
          m0 = MFMA(a, wb0, m0);
          m1 = MFMA(a, wb1, m1);
          o0 = MFMA(a, qb0, o0);
          o1 = MFMA(a, qb1, o1);
        }
#pragma unroll
        for (int rt = 0; rt < 2; ++rt) {
          f4 mm = rt ? m1 : m0;
          const us4 uu = rt ? u1 : u0;
          const int r = rt * 16 + lr;
#pragma unroll
          for (int rr = 0; rr < 4; ++rr)
            uts[wv * 16 + rg4 + rr][r] = f2bf(bf2f(uu[rr]) - mm[rr]);
        }
      }
      __syncthreads();
      {
        bf8v a2 = *(const bf8v*)&uts[wv * 16 + lr][kg8];
        {
          bf8v lb0 = *(const bf8v*)&las[lr][kg8];
          bf8v lb1 = *(const bf8v*)&las[16 + lr][kg8];
          o0 = MFMA(a2, lb0, o0);
          o1 = MFMA(a2, lb1, o1);
        }
#pragma unroll
        for (int rt = 0; rt < 2; ++rt) {
          f4 oo = rt ? o1 : o0;
          const int r = rt * 16 + lr;
          us4 st;
#pragma unroll
          for (int rr = 0; rr < 4; ++rr) st[rr] = f2bf(oo[rr]);
          *(us4*)(dout + ((size_t)(b * 4096 + l0 + r) * 4 + h) * 256 + c0 + wv * 16 + rg4) = st;
        }
#pragma unroll
        for (int d = 0; d < 16; ++d) {
          const int swzd = ((2 * d + (lr >> 3)) & 3) << 3;
          bf8v bb = *(const bf8v*)&kts[d * 16 + lr][kg8 ^ swzd];
          sacc[d] = MFMA(a2, bb, sacc[d]);
        }
#pragma unroll
        for (int d = 0; d < 16; ++d) {
#pragma unroll
          for (int rr = 0; rr < 4; ++rr)
            sbf[wv * 16 + rg4 + rr][d * 16 + lr] = f2bf(sacc[d][rr]);
        }
      }
      __syncthreads();
    }
    return;
  }
  if (blk < 544) {  // ===== 25-tap FIR (fl branch) =====
    const int fb = blk - 32;
    const int l0 = (fb & 63) * 64;
    const int by = fb >> 6;
    const int b = by >> 2, cb = by & 3;
    const int c = cb * 256 + tid;
    __shared__ u16t sm[88][256];
    for (int i = 0; i < 88; ++i) {
      int ls = l0 - 24 + i;
      sm[i][tid] = (ls >= 0) ? vc[((size_t)b * 4096 + ls) * 1024 + c] : (u16t)0;
    }
    __syncthreads();
    float w25[25];
#pragma unroll
    for (int j = 0; j < 25; ++j) w25[j] = w25g[c * 25 + j];
    float x[25];
#pragma unroll
    for (int j = 0; j < 25; ++j) x[j] = bf2f(sm[j][tid]);
    for (int ll = 0; ll < 64; ++ll) {
      float yl = 0.f;
#pragma unroll
      for (int j = 0; j < 25; ++j) yl += x[j] * w25[j];
      fl[((size_t)b * 4096 + l0 + ll) * 1024 + c] = f2bf(yl);
      if (ll < 63) {
#pragma unroll
        for (int j = 0; j < 24; ++j) x[j] = x[j + 1];
        x[24] = bf2f(sm[ll + 25][tid]);
      }
    }
    return;
  }
  if (blk < 672) {  // ===== pad W1 f32->bf16 =====
    for (size_t idx = (size_t)(blk - 544) * 256 + tid; idx < (size_t)2304 * 1152;
         idx += (size_t)128 * 256) {
      int n = (int)(idx / 1152), k = (int)(idx % 1152);
      W1p[idx] = (n < 2288 && k < 1144) ? f2bf(W1[(size_t)n * 1144 + k]) : (u16t)0;
    }
    return;
  }
  // ===== pack Wo f32->bf16 =====
  for (size_t i = (size_t)(blk - 672) * 256 + tid; i < 262144; i += (size_t)64 * 256) {
    f4 v = *(const f4*)&Wo[i * 4];
    us4 o;
#pragma unroll
    for (int e = 0; e < 4; ++e) o[e] = f2bf(v[e]);
    *(us4*)&wob[i * 4] = o;
  }
}

// ---------- on-the-fly small FIR branches (K=3,7,1) from vc ----------
__device__ __forceinline__ void fir_otf(const u16t* __restrict__ vc,
    const float* __restrict__ w3g, const float* __restrict__ w7g,
    const float* __restrict__ w1g, int b, int lseq, int c0,
    float ys[4], float ym[4], float yi[4]) {
  float xs[7][4];
#pragma unroll
  for (int j = 0; j < 7; ++j) {
    int ls = lseq - 6 + j;
    if (ls >= 0) {
      us4 v = *(const us4*)&vc[((size_t)b * 4096 + ls) * 1024 + c0];
#pragma unroll
      for (int e = 0; e < 4; ++e) xs[j][e] = bf2f(v[e]);
    } else {
#pragma unroll
      for (int e = 0; e < 4; ++e) xs[j][e] = 0.f;
    }
  }
#pragma unroll
  for (int e = 0; e < 4; ++e) {
    const int c = c0 + e;
    ys[e] = xs[4][e] * w3g[c * 3] + xs[5][e] * w3g[c * 3 + 1] + xs[6][e] * w3g[c * 3 + 2];
    float m_ = 0.f;
#pragma unroll
    for (int j = 0; j < 7; ++j) m_ += xs[j][e] * w7g[c * 7 + j];
    ym[e] = m_;
    yi[e] = xs[6][e] * w1g[c];
  }
}

// ---------- per-(b,l): stats + entropy + cross -> router_in (r10-proven) ----------
__global__ __launch_bounds__(256) void features_kernel(const float* __restrict__ hid,
    const u16t* __restrict__ vc, const float* __restrict__ w3g, const float* __restrict__ w7g,
    const float* __restrict__ w1g, const u16t* __restrict__ fl, const u16t* __restrict__ dlt,
    u16t* __restrict__ router) {
  const int m = blockIdx.x, tid = threadIdx.x;
  const int h = tid >> 6, l = tid & 63;
  const int b = m >> 12, lseq = m & 4095;
  const int c0 = h * 256 + l * 4;
  const size_t base = (size_t)m * 1024 + c0;
  float x[5][4];
  fir_otf(vc, w3g, w7g, w1g, b, lseq, c0, x[0], x[1], x[4]);
  {
    us4 v2 = *(const us4*)&fl[base];
    us4 v3 = *(const us4*)&dlt[base];
#pragma unroll
    for (int e = 0; e < 4; ++e) { x[2][e] = bf2f(v2[e]); x[3][e] = bf2f(v3[e]); }
  }
  float s1[5], s2[5], mx[5];
#pragma unroll
  for (int br = 0; br < 5; ++br) {
    float a = 0.f, bq = 0.f, m_ = -1e30f;
#pragma unroll
    for (int e = 0; e < 4; ++e) {
      a += x[br][e]; bq += x[br][e] * x[br][e]; m_ = fmaxf(m_, x[br][e]);
    }
    s1[br] = wsum(a); s2[br] = wsum(bq); mx[br] = wmax(m_);
  }
  float ent[5];
#pragma unroll
  for (int br = 0; br < 5; ++br) {
    float e_ = 0.f;
#pragma unroll
    for (int e = 0; e < 4; ++e) e_ += expf(x[br][e] - mx[br]);
    float es = wsum(e_);
    float hn = 0.f;
#pragma unroll
    for (int e = 0; e < 4; ++e) {
      float pv = expf(x[br][e] - mx[br]) / es;
      hn += pv * logf(pv + 1e-8f);
    }
    ent[br] = -wsum(hn);
  }
  float dt[10];
  {
    int pi = 0;
#pragma unroll
    for (int i = 0; i < 5; ++i)
#pragma unroll
      for (int j = i + 1; j < 5; ++j) {
        float d = 0.f;
#pragma unroll
        for (int e = 0; e < 4; ++e) d += x[i][e] * x[j][e];
        dt[pi] = wsum(d);
        ++pi;
      }
  }
  if (l == 0) {
    u16t* rp = router + (size_t)m * 1152 + 1024;
#pragma unroll
    for (int br = 0; br < 5; ++br) {
      float mean = s1[br] * (1.f / 256.f);
      float var = (s2[br] - s1[br] * s1[br] * (1.f / 256.f)) * (1.f / 255.f);
      rp[br * 16 + 0 + h] = f2bf(mean);
      rp[br * 16 + 4 + h] = f2bf(var);
      rp[br * 16 + 8 + h] = f2bf(mx[br]);
      rp[br * 16 + 12 + h] = f2bf(ent[br]);
    }
    int pi = 0;
#pragma unroll
    for (int i = 0; i < 5; ++i)
#pragma unroll
      for (int j = i + 1; j < 5; ++j) {
        float den = sqrtf(s2[i]) * sqrtf(s2[j]) + 1e-8f;
        rp[80 + pi * 4 + h] = f2bf(dt[pi] / den);
        ++pi;
      }
  }
  {
    f4 hv = *(const f4*)&hid[(size_t)m * 1024 + tid * 4];
    us4 hv4;
#pragma unroll
    for (int e = 0; e < 4; ++e) hv4[e] = f2bf(hv[e]);
    *(us4*)&router[(size_t)m * 1152 + tid * 4] = hv4;
  }
  if (tid < 8) router[(size_t)m * 1152 + 1144 + tid] = 0;
}

// ---------- fused W2 logits + softmax + floor + mix + RMSNorm ----------
__global__ __launch_bounds__(256) void route_mix(const u16t* __restrict__ hrt,
    const float* __restrict__ W2, const float* __restrict__ b2,
    const u16t* __restrict__ vc, const float* __restrict__ w3g,
    const float* __restrict__ w7g, const float* __restrict__ w1g,
    const u16t* __restrict__ fl, const u16t* __restrict__ dlt,
    const float* __restrict__ normw, u16t* __restrict__ mixed) {
  const int m = blockIdx.x, tid = threadIdx.x;
  const int h = tid >> 6, l = tid & 63;
  float acc[5];
#pragma unroll
  for (int n = 0; n < 5; ++n) acc[n] = 0.f;
  for (int kk = l * 4; kk < 2288; kk += 256) {
    us4 hv = *(const us4*)&hrt[(size_t)m * 2304 + kk];
    float hf[4];
#pragma unroll
    for (int e = 0; e < 4; ++e) hf[e] = bf2f(hv[e]);
#pragma unroll
    for (int n = 0; n < 5; ++n) {
      f4 wv4 = *(const f4*)&W2[(size_t)(h * 5 + n) * 2288 + kk];
#pragma unroll
      for (int e = 0; e < 4; ++e) acc[n] += hf[e] * wv4[e];
    }
  }
  float p5[5];
  {
    float lg[5];
#pragma unroll
    for (int n = 0; n < 5; ++n) lg[n] = wsum(acc[n]) + b2[h * 5 + n];
    float mxv = lg[0];
#pragma unroll
    for (int n = 1; n < 5; ++n) mxv = fmaxf(mxv, lg[n]);
    float es = 0.f, ev[5];
#pragma unroll
    for (int n = 0; n < 5; ++n) { ev[n] = expf(lg[n] - mxv); es += ev[n]; }
#pragma unroll
    for (int n = 0; n < 5; ++n) p5[n] = (ev[n] / es) * 0.95f + 0.01f;
  }
  const int b = m >> 12, lseq = m & 4095;
  const int c0 = h * 256 + l * 4;
  const size_t base = (size_t)m * 1024 + c0;
  float x[5][4];
  fir_otf(vc, w3g, w7g, w1g, b, lseq, c0, x[0], x[1], x[4]);
  {
    us4 v2 = *(const us4*)&fl[base];
    us4 v3 = *(const us4*)&dlt[base];
#pragma unroll
    for (int e = 0; e < 4; ++e) { x[2][e] = bf2f(v2[e]); x[3][e] = bf2f(v3[e]); }
  }
  float o[4] = {0.f, 0.f, 0.f, 0.f};
#pragma unroll
  for (int br = 0; br < 5; ++br)
#pragma unroll
    for (int e = 0; e < 4; ++e) o[e] += p5[br] * x[br][e];
  float ss = 0.f;
#pragma unroll
  for (int e = 0; e < 4; ++e) ss += o[e] * o[e];
  ss = wsum(ss);
  float sc = rsqrtf(ss * (1.f / 256.f) + 1e-5f);
  f4 nw = *(const f4*)&normw[l * 4];
  us4 ov;
#pragma unroll
  for (int e = 0; e < 4; ++e) ov[e] = f2bf(o[e] * sc * nw[e]);
  *(us4*)&mixed[base] = ov;
}

// ---------- launcher ----------
extern "C" void kernel_launch(void* const* d_in, const int* in_sizes, int n_in,
                              void* d_out, int out_size, void* d_ws, size_t ws_size,
                              hipStream_t stream) {
  (void)in_sizes; (void)n_in; (void)out_size; (void)ws_size;
  const float* hid = (const float*)d_in[0];
  const float* Wq = (const float*)d_in[1];
  const float* Wk = (const float*)d_in[2];
  const float* Wv = (const float*)d_in[3];
  const float* wqc = (const float*)d_in[4];
  const float* wkc = (const float*)d_in[5];
  const float* wvc = (const float*)d_in[6];
  const float* Wb = (const float*)d_in[7];
  const float* fsw = (const float*)d_in[8];
  const float* fmw = (const float*)d_in[9];
  const float* flw = (const float*)d_in[10];
  const float* fiw = (const float*)d_in[11];
  const float* W1 = (const float*)d_in[12];
  const float* b1 = (const float*)d_in[13];
  const float* W2 = (const float*)d_in[14];
  const float* b2 = (const float*)d_in[15];
  const float* nwt = (const float*)d_in[16];
  const float* Wo = (const float*)d_in[17];
  float* out = (float*)d_out;

  char* wsp = (char*)d_ws;
  const size_t S = (size_t)2 * 4096 * 1024 * 2;  // 16 MiB per (B,L,D) bf16 buffer
  u16t* ql = (u16t*)(wsp + 0 * S);
  u16t* kl = (u16t*)(wsp + 1 * S);
  u16t* vl = (u16t*)(wsp + 2 * S);
  u16t* qc = (u16t*)(wsp + 3 * S);
  u16t* kc = (u16t*)(wsp + 4 * S);
  u16t* vc = (u16t*)(wsp + 5 * S);
  u16t* ubuf = (u16t*)(wsp + 6 * S);
  u16t* wbuf = (u16t*)(wsp + 7 * S);
  char* p = wsp + 8 * S;
  u16t* router = (u16t*)p; p += (size_t)8192 * 1152 * 2;
  u16t* hrt = (u16t*)p;    p += (size_t)8192 * 2304 * 2;
  u16t* w1p = (u16t*)p;    p += (size_t)2304 * 1152 * 2;
  u16t* wob = (u16t*)p;    p += (size_t)1024 * 1024 * 2;
  // buffer reuse (lifetime-checked):
  u16t* hidb = qc;          // dead before conv writes qc
  u16t* wqb = kc;           // dead before conv writes kc
  u16t* wkb = kc + 1048576;
  u16t* wvb = kc + 2097152;
  u16t* kbeta = ql;   // ql dead after conv; kbeta dead after chunk_uw
  u16t* vbeta = kl;   // kl dead after conv; vbeta dead after chunk_uw
  u16t* dlt = kl;     // scan output
  u16t* f_l = vl;     // vl dead after conv; written by scan-shadow FIR
  u16t* mixed = wbuf; // wbuf (wg) dead after scan

  dim3 blk(256);
  pack_all<<<dim3(11264), blk, 0, stream>>>(hid, Wq, Wk, Wv, hidb, wqb, wkb, wvb);
  gemm_qkv3<<<dim3(8, 64, 3), blk, 0, stream>>>(hidb, wqb, wkb, wvb, ql, kl, vl);
  conv4_silu<<<dim3(64, 8, 3), blk, 0, stream>>>(ql, kl, vl, wqc, wkc, wvc, qc, kc, vc);
  prep_kernel<<<dim3(8192), blk, 0, stream>>>(qc, kc, vc, hid, Wb, kbeta, vbeta);
  chunk_uw<<<dim3(1024), blk, 0, stream>>>(kc, kbeta, vbeta, ubuf, wbuf);
  delta_scan<<<dim3(736), blk, 0, stream>>>(qc, kc, ubuf, wbuf, dlt, vc, flw, f_l,
                                            W1, w1p, Wo, wob);
  features_kernel<<<dim3(8192), blk, 0, stream>>>(hid, vc, fsw, fmw, fiw, f_l, dlt, router);
  gemm_bt<false, 1><<<dim3(18, 64), blk, 0, stream>>>(router, w1p, hrt, b1, 1152, 1152, 1152, 2304);
  route_mix<<<dim3(8192), blk, 0, stream>>>(hrt, W2, b2, vc, fsw, fmw, fiw, f_l, dlt, nwt, mixed);
  gemm_bt<true, 0><<<dim3(8, 64), blk, 0, stream>>>(mixed, wob, out, nullptr, 1024, 1024, 1024, 1024);
}

// Round 14
// 992.356 us; speedup vs baseline: 1.6173x; 1.0471x over previous
//
#include <hip/hip_runtime.h>
#include <stdint.h>

// ---------- types / helpers ----------
typedef unsigned short u16t;
typedef u16t us4 __attribute__((ext_vector_type(4)));
typedef u16t us8 __attribute__((ext_vector_type(8)));
typedef __bf16 bf8v __attribute__((ext_vector_type(8)));
typedef float f4 __attribute__((ext_vector_type(4)));

#define MFMA(a, b, c) __builtin_amdgcn_mfma_f32_16x16x32_bf16((a), (b), (c), 0, 0, 0)
#define GLOAD_LDS16(g, l) __builtin_amdgcn_global_load_lds( \
    (const __attribute__((address_space(1))) void*)(g),     \
    (__attribute__((address_space(3))) void*)(l), 16, 0, 0)

__device__ __forceinline__ float bf2f(u16t u) {
  union { unsigned int i; float f; } c; c.i = ((unsigned int)u) << 16; return c.f;
}
__device__ __forceinline__ u16t f2bf(float f) {
  union { float f; unsigned int i; } c; c.f = f;
  return (u16t)((c.i + 0x7FFFu + ((c.i >> 16) & 1u)) >> 16);
}
__device__ __forceinline__ float wsum(float v) {
#pragma unroll
  for (int o = 32; o > 0; o >>= 1) v += __shfl_xor(v, o);
  return v;
}
__device__ __forceinline__ float wmax(float v) {
#pragma unroll
  for (int o = 32; o > 0; o >>= 1) v = fmaxf(v, __shfl_xor(v, o));
  return v;
}

// ---------- pack hid+Wq+Wk+Wv f32->bf16 + transpose small FIR weights ----------
__global__ __launch_bounds__(256) void pack_all(const float* __restrict__ hid,
    const float* __restrict__ Wq, const float* __restrict__ Wk, const float* __restrict__ Wv,
    const float* __restrict__ fsw, const float* __restrict__ fmw,
    u16t* __restrict__ hidb, u16t* __restrict__ wqb, u16t* __restrict__ wkb,
    u16t* __restrict__ wvb, float* __restrict__ w3t, float* __restrict__ w7t) {
  const int g = blockIdx.x * 256 + threadIdx.x;
  if (g < 2883584) {  // f4-group packs
    const float* src; u16t* dst; int off;
    if (g < 2097152) { src = hid; dst = hidb; off = g; }
    else if (g < 2359296) { src = Wq; dst = wqb; off = g - 2097152; }
    else if (g < 2621440) { src = Wk; dst = wkb; off = g - 2359296; }
    else { src = Wv; dst = wvb; off = g - 2621440; }
    f4 v = *(const f4*)&src[(size_t)off * 4];
    us4 o;
#pragma unroll
    for (int e = 0; e < 4; ++e) o[e] = f2bf(v[e]);
    *(us4*)&dst[(size_t)off * 4] = o;
    return;
  }
  int idx = g - 2883584;  // scalar transposes (one-time, tiny)
  if (idx < 3072) {
    int j = idx >> 10, c = idx & 1023;
    w3t[idx] = fsw[c * 3 + j];
  } else if (idx < 10240) {
    int idx2 = idx - 3072;
    int j = idx2 / 1024, c = idx2 & 1023;
    w7t[idx2] = fmw[c * 7 + j];
  }
}

// ---------- GEMM (all-bf16 operands): C[M,N] = A[M,K] @ Bt[N,K]^T ----------
template <bool CF32, int EPI>
__device__ __forceinline__ void gemm_body(const u16t* __restrict__ A,
    const u16t* __restrict__ Bt, void* __restrict__ Cv, const float* __restrict__ bias,
    int K, int lda, int ldb, int ldc, int m0, int n0) {
  __shared__ u16t As[128][32];
  __shared__ u16t Bs[128][32];
  const int tid = threadIdx.x;
  const int wv = tid >> 6, l = tid & 63;
  const int wr = wv >> 1, wc = wv & 1;
  const int lr = l & 15, kg8 = (l >> 4) * 8, rg4 = (l >> 4) * 4;
  const f4 zf = {0.f, 0.f, 0.f, 0.f};
  f4 acc[4][4];
#pragma unroll
  for (int i = 0; i < 4; ++i)
#pragma unroll
    for (int j = 0; j < 4; ++j) acc[i][j] = zf;

  const u16t* ga = A + (size_t)(m0 + wv * 32 + (l >> 2)) * lda + (l & 3) * 8;
  const u16t* gb = Bt + (size_t)(n0 + wv * 32 + (l >> 2)) * ldb + (l & 3) * 8;
  u16t* la0 = &As[wv * 32][0];
  u16t* la1 = &As[wv * 32 + 16][0];
  u16t* lb0 = &Bs[wv * 32][0];
  u16t* lb1 = &Bs[wv * 32 + 16][0];

  for (int kt = 0; kt < K; kt += 32) {
    GLOAD_LDS16(ga + kt, la0);
    GLOAD_LDS16(ga + (size_t)16 * lda + kt, la1);
    GLOAD_LDS16(gb + kt, lb0);
    GLOAD_LDS16(gb + (size_t)16 * ldb + kt, lb1);
    __syncthreads();
    bf8v af[4], bg[4];
#pragma unroll
    for (int f = 0; f < 4; ++f) af[f] = *(const bf8v*)&As[wr * 64 + f * 16 + lr][kg8];
#pragma unroll
    for (int f = 0; f < 4; ++f) bg[f] = *(const bf8v*)&Bs[wc * 64 + f * 16 + lr][kg8];
#pragma unroll
    for (int i = 0; i < 4; ++i)
#pragma unroll
      for (int j = 0; j < 4; ++j) acc[i][j] = MFMA(af[i], bg[j], acc[i][j]);
    __syncthreads();
  }
#pragma unroll
  for (int i = 0; i < 4; ++i) {
    const int rb = m0 + wr * 64 + i * 16 + rg4;
#pragma unroll
    for (int j = 0; j < 4; ++j) {
      const int cb = n0 + wc * 64 + j * 16 + lr;
#pragma unroll
      for (int r = 0; r < 4; ++r) {
        float x = acc[i][j][r];
        if (EPI == 1) {
          float xx = x + ((cb < 2288) ? bias[cb] : 0.f);
          x = 0.5f * xx * (1.f + erff(xx * 0.70710678118f));
        }
        if (CF32)
          ((float*)Cv)[(size_t)(rb + r) * ldc + cb] = x;
        else
          ((u16t*)Cv)[(size_t)(rb + r) * ldc + cb] = f2bf(x);
      }
    }
  }
}

template <bool CF32, int EPI>
__global__ __launch_bounds__(256) void gemm_bt(const u16t* __restrict__ Av,
    const u16t* __restrict__ Btv, void* __restrict__ Cv, const float* __restrict__ bias,
    int K, int lda, int ldb, int ldc) {
  gemm_body<CF32, EPI>(Av, Btv, Cv, bias, K, lda, ldb, ldc,
                       blockIdx.y * 128, blockIdx.x * 128);
}

__global__ __launch_bounds__(256) void gemm_qkv3(const u16t* __restrict__ A,
    const u16t* __restrict__ B0, const u16t* __restrict__ B1,
    const u16t* __restrict__ B2, u16t* __restrict__ C0, u16t* __restrict__ C1,
    u16t* __restrict__ C2v) {
  const int z = blockIdx.z;
  const u16t* Bt = (z == 0) ? B0 : ((z == 1) ? B1 : B2);
  u16t* C = (z == 0) ? C0 : ((z == 1) ? C1 : C2v);
  gemm_body<false, 0>(A, Bt, C, nullptr, 1024, 1024, 1024, 1024,
                      blockIdx.y * 128, blockIdx.x * 128);
}

// ---------- logits GEMM: logits[8192][32] = hrt[8192][2304] @ W2b[32][2304]^T + b2 ----------
__global__ __launch_bounds__(256) void logits_gemm(const u16t* __restrict__ hrt,
    const u16t* __restrict__ W2b, const float* __restrict__ b2, float* __restrict__ logits) {
  __shared__ u16t As[128][32];
  __shared__ u16t Bs[32][32];
  const int tid = threadIdx.x;
  const int wv = tid >> 6, l = tid & 63;
  const int lr = l & 15, kg8 = (l >> 4) * 8, rg4 = (l >> 4) * 4;
  const int m0 = blockIdx.x * 128;
  const f4 zf = {0.f, 0.f, 0.f, 0.f};
  f4 acc[2][2];
#pragma unroll
  for (int i = 0; i < 2; ++i)
#pragma unroll
    for (int j = 0; j < 2; ++j) acc[i][j] = zf;

  const u16t* ga = hrt + (size_t)(m0 + wv * 32 + (l >> 2)) * 2304 + (l & 3) * 8;
  const u16t* gb = W2b + (size_t)(l >> 2) * 2304 + (l & 3) * 8;
  u16t* la0 = &As[wv * 32][0];
  u16t* la1 = &As[wv * 32 + 16][0];

  for (int kt = 0; kt < 2304; kt += 32) {
    GLOAD_LDS16(ga + kt, la0);
    GLOAD_LDS16(ga + (size_t)16 * 2304 + kt, la1);
    if (wv == 0) {
      GLOAD_LDS16(gb + kt, &Bs[0][0]);
      GLOAD_LDS16(gb + (size_t)16 * 2304 + kt, &Bs[16][0]);
    }
    __syncthreads();
    bf8v af[2], bg[2];
#pragma unroll
    for (int f = 0; f < 2; ++f) af[f] = *(const bf8v*)&As[wv * 32 + f * 16 + lr][kg8];
#pragma unroll
    for (int f = 0; f < 2; ++f) bg[f] = *(const bf8v*)&Bs[f * 16 + lr][kg8];
#pragma unroll
    for (int i = 0; i < 2; ++i)
#pragma unroll
      for (int j = 0; j < 2; ++j) acc[i][j] = MFMA(af[i], bg[j], acc[i][j]);
    __syncthreads();
  }
#pragma unroll
  for (int i = 0; i < 2; ++i) {
    const int rb = m0 + wv * 32 + i * 16 + rg4;
#pragma unroll
    for (int j = 0; j < 2; ++j) {
      const int cb = j * 16 + lr;
#pragma unroll
      for (int r = 0; r < 4; ++r) {
        float x = acc[i][j][r];
        if (cb < 20) x += b2[cb];
        logits[(size_t)(rb + r) * 32 + cb] = x;
      }
    }
  }
}

// ---------- depthwise causal conv K=4 + SiLU (sliding-window registers) ----------
__global__ __launch_bounds__(256) void conv4_silu(
    const u16t* __restrict__ qlin, const u16t* __restrict__ klin, const u16t* __restrict__ vlin,
    const float* __restrict__ wq, const float* __restrict__ wk, const float* __restrict__ wvv,
    u16t* __restrict__ qc, u16t* __restrict__ kc, u16t* __restrict__ vc) {
  const int tid = threadIdx.x;
  const int l0 = blockIdx.x * 64;
  const int b = blockIdx.y >> 2, cb = blockIdx.y & 3;
  const int z = blockIdx.z;
  const u16t* in_ = (z == 0) ? qlin : ((z == 1) ? klin : vlin);
  const float* w_ = (z == 0) ? wq : ((z == 1) ? wk : wvv);
  u16t* out_ = (z == 0) ? qc : ((z == 1) ? kc : vc);
  const int c = cb * 256 + tid;
  __shared__ u16t sm[67][256];
  for (int i = 0; i < 67; ++i) {
    int ls = l0 - 3 + i;
    sm[i][tid] = (ls >= 0) ? in_[((size_t)b * 4096 + ls) * 1024 + c] : (u16t)0;
  }
  __syncthreads();
  f4 w4 = *(const f4*)&w_[c * 4];
  float x0 = bf2f(sm[0][tid]), x1 = bf2f(sm[1][tid]), x2 = bf2f(sm[2][tid]);
  for (int ll = 0; ll < 64; ++ll) {
    float x3 = bf2f(sm[ll + 3][tid]);
    float y = x0 * w4[0] + x1 * w4[1] + x2 * w4[2] + x3 * w4[3];
    y = y / (1.f + expf(-y));
    out_[((size_t)b * 4096 + l0 + ll) * 1024 + c] = f2bf(y);
    x0 = x1; x1 = x2; x2 = x3;
  }
}

// ---------- fused beta + l2norm(q,k) + kb/vb ----------
__global__ __launch_bounds__(256) void prep_kernel(u16t* __restrict__ qc, u16t* __restrict__ kc,
    const u16t* __restrict__ vc, const float* __restrict__ hid, const float* __restrict__ Wb,
    u16t* __restrict__ kbeta, u16t* __restrict__ vbeta) {
  const int m = blockIdx.x, tid = threadIdx.x;
  const int h = tid >> 6, l = tid & 63;
  float bacc = 0.f;
#pragma unroll
  for (int it = 0; it < 4; ++it) {
    int kk = l * 4 + it * 256;
    f4 hv = *(const f4*)&hid[(size_t)m * 1024 + kk];
    f4 wv4 = *(const f4*)&Wb[(size_t)h * 1024 + kk];
#pragma unroll
    for (int e = 0; e < 4; ++e) bacc += hv[e] * wv4[e];
  }
  const float bet = 1.f / (1.f + expf(-wsum(bacc)));
  const size_t base = (size_t)m * 1024 + h * 256 + l * 4;
  us4 q4 = *(const us4*)&qc[base];
  float qf[4]; float ss = 0.f;
#pragma unroll
  for (int e = 0; e < 4; ++e) { qf[e] = bf2f(q4[e]); ss += qf[e] * qf[e]; }
  float qsc = rsqrtf(wsum(ss) + 1e-12f);
  us4 qo;
#pragma unroll
  for (int e = 0; e < 4; ++e) qo[e] = f2bf(qf[e] * qsc);
  *(us4*)&qc[base] = qo;
  us4 k4 = *(const us4*)&kc[base];
  float kf[4]; ss = 0.f;
#pragma unroll
  for (int e = 0; e < 4; ++e) { kf[e] = bf2f(k4[e]); ss += kf[e] * kf[e]; }
  float ksc = rsqrtf(wsum(ss) + 1e-12f);
  us4 ko, kbo;
#pragma unroll
  for (int e = 0; e < 4; ++e) {
    float kn = kf[e] * ksc;
    ko[e] = f2bf(kn);
    kbo[e] = f2bf(kn * bet);
  }
  *(us4*)&kc[base] = ko;
  *(us4*)&kbeta[base] = kbo;
  us4 v4 = *(const us4*)&vc[base];
  us4 vo;
#pragma unroll
  for (int e = 0; e < 4; ++e) vo[e] = f2bf(bf2f(v4[e]) * bet);
  *(us4*)&vbeta[base] = vo;
}

// ---------- per-chunk triangular inverse, u = T@vb, w = T@kb (MFMA phase 1) ----------
__global__ __launch_bounds__(256) void chunk_uw(const u16t* __restrict__ kn,
    const u16t* __restrict__ kbeta, const u16t* __restrict__ vbeta,
    u16t* __restrict__ ug, u16t* __restrict__ wg) {
  const int tid = threadIdx.x;
  const int bh = blockIdx.x >> 7, ci = blockIdx.x & 127;
  const int b = bh >> 2, h = bh & 3;
  const int l0 = ci * 32;
  __shared__ u16t kns[32][264], kbs[32][264], vbs[32][264];
  __shared__ float attn_s[32][33];
  const int sr = tid >> 5, sd8 = (tid & 31) * 8;
  const size_t rowbase = (size_t)b * 4096 * 1024 + (size_t)h * 256;
#pragma unroll
  for (int i = 0; i < 4; ++i) {
    int r = i * 8 + sr;
    size_t g = rowbase + (size_t)(l0 + r) * 1024 + sd8;
    *(us8*)&kns[r][sd8] = *(const us8*)&kn[g];
    *(us8*)&kbs[r][sd8] = *(const us8*)&kbeta[g];
    *(us8*)&vbs[r][sd8] = *(const us8*)&vbeta[g];
  }
  __syncthreads();
  {
    const int wv = tid >> 6, l = tid & 63;
    const int lr = l & 15, kg8 = (l >> 4) * 8, rg4 = (l >> 4) * 4;
    const int rq = wv >> 1, rk = wv & 1;
    f4 t4 = {0.f, 0.f, 0.f, 0.f};
#pragma unroll
    for (int ks = 0; ks < 8; ++ks) {
      bf8v a = *(const bf8v*)&kbs[rq * 16 + lr][ks * 32 + kg8];
      bf8v bb = *(const bf8v*)&kns[rk * 16 + lr][ks * 32 + kg8];
      t4 = MFMA(a, bb, t4);
    }
    const int colj = rk * 16 + lr;
#pragma unroll
    for (int rr = 0; rr < 4; ++rr) {
      const int rowr = rq * 16 + rg4 + rr;
      attn_s[rowr][colj] = (colj < rowr) ? -t4[rr] : 0.f;
    }
  }
  __syncthreads();
  if (tid < 32) {
    const int j = tid;
    for (int i = 1; i < 32; ++i) {
      float aij = attn_s[i][j];
      float upd = 0.f;
#pragma unroll 1
      for (int k = 1; k < 31; ++k) {
        float aik = __shfl(aij, k);
        float akj = (k > j && k < i) ? attn_s[k][j] : 0.f;
        upd += aik * akj;
      }
      if (j < i) attn_s[i][j] = aij + upd;
    }
    attn_s[j][j] = 1.f;
  }
  __syncthreads();
  {
    const int r = tid >> 3, cg = (tid & 7) * 32;
    float ua[32], wa[32];
#pragma unroll
    for (int e = 0; e < 32; ++e) { ua[e] = 0.f; wa[e] = 0.f; }
    for (int j = 0; j < 32; ++j) {
      float a = attn_s[r][j];
#pragma unroll
      for (int e0 = 0; e0 < 32; e0 += 8) {
        us8 v8 = *(const us8*)&vbs[j][cg + e0];
        us8 k8 = *(const us8*)&kbs[j][cg + e0];
#pragma unroll
        for (int e = 0; e < 8; ++e) {
          ua[e0 + e] += a * bf2f(v8[e]);
          wa[e0 + e] += a * bf2f(k8[e]);
        }
      }
    }
    const size_t ob = ((size_t)bh * 4096 + l0 + r) * 256 + cg;
#pragma unroll
    for (int e0 = 0; e0 < 32; e0 += 8) {
      us8 pu, pw;
#pragma unroll
      for (int e = 0; e < 8; ++e) { pu[e] = f2bf(ua[e0 + e]); pw[e] = f2bf(wa[e0 + e]); }
      *(us8*)&ug[ob + e0] = pu;
      *(us8*)&wg[ob + e0] = pw;
    }
  }
}

// ---------- fused launch: 0-31 scan | 32-543 FIR-25 | 544-671 padW1 |
// 672-735 packWo | 736-751 packW2 ----------
__global__ __launch_bounds__(256, 1) void delta_scan(const u16t* __restrict__ qn,
    const u16t* __restrict__ kn, const u16t* __restrict__ ug, const u16t* __restrict__ wg,
    u16t* __restrict__ dout, const u16t* __restrict__ vc, const float* __restrict__ w25g,
    u16t* __restrict__ fl, const float* __restrict__ W1, u16t* __restrict__ W1p,
    const float* __restrict__ Wo, u16t* __restrict__ wob, const float* __restrict__ W2,
    u16t* __restrict__ W2b) {
  const int blk = blockIdx.x;
  const int tid = threadIdx.x;
  if (blk < 32) {  // ===== delta scan (r5-proven structure) =====
    const int bh = blk >> 2, vbidx = blk & 3;
    const int b = bh >> 2, h = bh & 3;
    const int c0 = vbidx * 64;
    const int wv = tid >> 6, l = tid & 63;
    const int lr = l & 15, kg8 = (l >> 4) * 8, rg4 = (l >> 4) * 4;

    __shared__ u16t qs[32][264], ks2[32][264], wss[32][264];
    __shared__ u16t kts[256][40];
    __shared__ u16t sbf[64][264];
    __shared__ u16t las[32][40];
    __shared__ u16t uts[64][40];

    {
      u16t* sp = &sbf[0][0];
      for (int i = tid; i < 64 * 264; i += 256) sp[i] = 0;
    }
    const f4 zf = {0.f, 0.f, 0.f, 0.f};
    f4 sacc[16];
#pragma unroll
    for (int d = 0; d < 16; ++d) sacc[d] = zf;
    __syncthreads();

    const u16t* qb = qn + (size_t)b * 4096 * 1024 + (size_t)h * 256;
    const u16t* knb = kn + (size_t)b * 4096 * 1024 + (size_t)h * 256;
    const u16t* ub = ug + (size_t)bh * 4096 * 256;
    const u16t* wb = wg + (size_t)bh * 4096 * 256;
    const int sr = tid >> 5, sd8 = (tid & 31) * 8;

    us8 pq[4], pk[4], pw[4];
    us4 pu0, pu1;
#pragma unroll
    for (int i = 0; i < 4; ++i) {
      const int r = i * 8 + sr;
      pq[i] = *(const us8*)(qb + (size_t)r * 1024 + sd8);
      pk[i] = *(const us8*)(knb + (size_t)r * 1024 + sd8);
      pw[i] = *(const us8*)(wb + (size_t)r * 256 + sd8);
    }
    pu0 = *(const us4*)(ub + (size_t)lr * 256 + c0 + wv * 16 + rg4);
    pu1 = *(const us4*)(ub + (size_t)(16 + lr) * 256 + c0 + wv * 16 + rg4);

    for (int ci = 0; ci < 128; ++ci) {
      const int l0 = ci * 32;
#pragma unroll
      for (int i = 0; i < 4; ++i) {
        const int r = i * 8 + sr;
        *(us8*)&qs[r][sd8] = pq[i];
        *(us8*)&ks2[r][sd8] = pk[i];
        *(us8*)&wss[r][sd8] = pw[i];
      }
      const us4 u0 = pu0, u1 = pu1;
      __syncthreads();
      if (ci < 127) {
        const int l1 = l0 + 32;
#pragma unroll
        for (int i = 0; i < 4; ++i) {
          const int r = i * 8 + sr;
          pq[i] = *(const us8*)(qb + (size_t)(l1 + r) * 1024 + sd8);
          pk[i] = *(const us8*)(knb + (size_t)(l1 + r) * 1024 + sd8);
          pw[i] = *(const us8*)(wb + (size_t)(l1 + r) * 256 + sd8);
        }
        pu0 = *(const us4*)(ub + (size_t)(l1 + lr) * 256 + c0 + wv * 16 + rg4);
        pu1 = *(const us4*)(ub + (size_t)(l1 + 16 + lr) * 256 + c0 + wv * 16 + rg4);
      }
      {
        const int dk = tid;
        const int swz = ((dk >> 3) & 3) << 3;
#pragma unroll
        for (int r = 0; r < 32; r += 2) {
          unsigned int lo = ks2[r][dk], hi = ks2[r + 1][dk];
          *(unsigned int*)&kts[dk][r ^ swz] = lo | (hi << 16);
        }
      }
      {
        const int rq = wv >> 1, rk = wv & 1;
        f4 t4 = zf;
#pragma unroll
        for (int ks = 0; ks < 8; ++ks) {
          bf8v a = *(const bf8v*)&qs[rq * 16 + lr][ks * 32 + kg8];
          bf8v bb = *(const bf8v*)&ks2[rk * 16 + lr][ks * 32 + kg8];
          t4 = MFMA(a, bb, t4);
        }
        const int colj = rk * 16 + lr;
#pragma unroll
        for (int rr = 0; rr < 4; ++rr) {
          const int rowr = rq * 16 + rg4 + rr;
          las[rowr][colj] = (colj <= rowr) ? f2bf(t4[rr]) : (u16t)0;
        }
      }
      f4 o0 = zf, o1 = zf;
      {
        f4 m0 = zf, m1 = zf;
#pragma unroll
        for (int ks = 0; ks < 8; ++ks) {
          bf8v a = *(const bf8v*)&sbf[wv * 16 + lr][ks * 32 + kg8];
          bf8v wb0 = *(const bf8v*)&wss[lr][ks * 32 + kg8];
          bf8v wb1 = *(const bf8v*)&wss[16 + lr][ks * 32 + kg8];
          bf8v qb0 = *(const bf8v*)&qs[lr][ks * 32 + kg8];
          bf8v qb1 = *(const bf8v*)&qs[16 + lr][ks * 32 + kg8];
          m0 = MFMA(a, wb0, m0);
          m1 = MFMA(a, wb1, m1);
          o0 = MFMA(a, qb0, o0);
          o1 = MFMA(a, qb1, o1);
        }
#pragma unroll
        for (int rt = 0; rt < 2; ++rt) {
          f4 mm = rt ? m1 : m0;
          const us4 uu = rt ? u1 : u0;
          const int r = rt * 16 + lr;
#pragma unroll
          for (int rr = 0; rr < 4; ++rr)
            uts[wv * 16 + rg4 + rr][r] = f2bf(bf2f(uu[rr]) - mm[rr]);
        }
      }
      __syncthreads();
      {
        bf8v a2 = *(const bf8v*)&uts[wv * 16 + lr][kg8];
        {
          bf8v lb0 = *(const bf8v*)&las[lr][kg8];
          bf8v lb1 = *(const bf8v*)&las[16 + lr][kg8];
          o0 = MFMA(a2, lb0, o0);
          o1 = MFMA(a2, lb1, o1);
        }
#pragma unroll
        for (int rt = 0; rt < 2; ++rt) {
          f4 oo = rt ? o1 : o0;
          const int r = rt * 16 + lr;
          us4 st;
#pragma unroll
          for (int rr = 0; rr < 4; ++rr) st[rr] = f2bf(oo[rr]);
          *(us4*)(dout + ((size_t)(b * 4096 + l0 + r) * 4 + h) * 256 + c0 + wv * 16 + rg4) = st;
        }
#pragma unroll
        for (int d = 0; d < 16; ++d) {
          const int swzd = ((2 * d + (lr >> 3)) & 3) << 3;
          bf8v bb = *(const bf8v*)&kts[d * 16 + lr][kg8 ^ swzd];
          sacc[d] = MFMA(a2, bb, sacc[d]);
        }
#pragma unroll
        for (int d = 0; d < 16; ++d) {
#pragma unroll
          for (int rr = 0; rr < 4; ++rr)
            sbf[wv * 16 + rg4 + rr][d * 16 + lr] = f2bf(sacc[d][rr]);
        }
      }
      __syncthreads();
    }
    return;
  }
  if (blk < 544) {  // ===== 25-tap FIR (fl branch) =====
    const int fb = blk - 32;
    const int l0 = (fb & 63) * 64;
    const int by = fb >> 6;
    const int b = by >> 2, cb = by & 3;
    const int c = cb * 256 + tid;
    __shared__ u16t sm[88][256];
    for (int i = 0; i < 88; ++i) {
      int ls = l0 - 24 + i;
      sm[i][tid] = (ls >= 0) ? vc[((size_t)b * 4096 + ls) * 1024 + c] : (u16t)0;
    }
    __syncthreads();
    float w25[25];
#pragma unroll
    for (int j = 0; j < 25; ++j) w25[j] = w25g[c * 25 + j];
    float x[25];
#pragma unroll
    for (int j = 0; j < 25; ++j) x[j] = bf2f(sm[j][tid]);
    for (int ll = 0; ll < 64; ++ll) {
      float yl = 0.f;
#pragma unroll
      for (int j = 0; j < 25; ++j) yl += x[j] * w25[j];
      fl[((size_t)b * 4096 + l0 + ll) * 1024 + c] = f2bf(yl);
      if (ll < 63) {
#pragma unroll
        for (int j = 0; j < 24; ++j) x[j] = x[j + 1];
        x[24] = bf2f(sm[ll + 25][tid]);
      }
    }
    return;
  }
  if (blk < 672) {  // ===== pad W1 f32->bf16 =====
    for (size_t idx = (size_t)(blk - 544) * 256 + tid; idx < (size_t)2304 * 1152;
         idx += (size_t)128 * 256) {
      int n = (int)(idx / 1152), k = (int)(idx % 1152);
      W1p[idx] = (n < 2288 && k < 1144) ? f2bf(W1[(size_t)n * 1144 + k]) : (u16t)0;
    }
    return;
  }
  if (blk < 736) {  // ===== pack Wo f32->bf16 =====
    for (size_t i = (size_t)(blk - 672) * 256 + tid; i < 262144; i += (size_t)64 * 256) {
      f4 v = *(const f4*)&Wo[i * 4];
      us4 o;
#pragma unroll
      for (int e = 0; e < 4; ++e) o[e] = f2bf(v[e]);
      *(us4*)&wob[i * 4] = o;
    }
    return;
  }
  // ===== pack W2 [20][2288] f32 -> W2b [32][2304] bf16 zero-padded =====
  for (size_t idx = (size_t)(blk - 736) * 256 + tid; idx < (size_t)32 * 2304;
       idx += (size_t)16 * 256) {
    int n = (int)(idx / 2304), k = (int)(idx % 2304);
    W2b[idx] = (n < 20 && k < 2288) ? f2bf(W2[(size_t)n * 2288 + k]) : (u16t)0;
  }
}

// ---------- on-the-fly small FIR branches (K=3,7,1), transposed weights ----------
__device__ __forceinline__ void fir_otf(const u16t* __restrict__ vc,
    const float* __restrict__ w3t, const float* __restrict__ w7t,
    const float* __restrict__ w1g, int b, int lseq, int c0,
    float ys[4], float ym[4], float yi[4]) {
  float xs[7][4];
#pragma unroll
  for (int j = 0; j < 7; ++j) {
    int ls = lseq - 6 + j;
    if (ls >= 0) {
      us4 v = *(const us4*)&vc[((size_t)b * 4096 + ls) * 1024 + c0];
#pragma unroll
      for (int e = 0; e < 4; ++e) xs[j][e] = bf2f(v[e]);
    } else {
#pragma unroll
      for (int e = 0; e < 4; ++e) xs[j][e] = 0.f;
    }
  }
  f4 w3v[3], w7v[7], w1v;
#pragma unroll
  for (int j = 0; j < 3; ++j) w3v[j] = *(const f4*)&w3t[j * 1024 + c0];
#pragma unroll
  for (int j = 0; j < 7; ++j) w7v[j] = *(const f4*)&w7t[j * 1024 + c0];
  w1v = *(const f4*)&w1g[c0];
#pragma unroll
  for (int e = 0; e < 4; ++e) {
    ys[e] = xs[4][e] * w3v[0][e] + xs[5][e] * w3v[1][e] + xs[6][e] * w3v[2][e];
    float m_ = 0.f;
#pragma unroll
    for (int j = 0; j < 7; ++j) m_ += xs[j][e] * w7v[j][e];
    ym[e] = m_;
    yi[e] = xs[6][e] * w1v[e];
  }
}

// ---------- per-(b,l): stats + entropy + cross -> router_in ----------
__global__ __launch_bounds__(256) void features_kernel(const float* __restrict__ hid,
    const u16t* __restrict__ vc, const float* __restrict__ w3t, const float* __restrict__ w7t,
    const float* __restrict__ w1g, const u16t* __restrict__ fl, const u16t* __restrict__ dlt,
    u16t* __restrict__ router) {
  const int m = blockIdx.x, tid = threadIdx.x;
  const int h = tid >> 6, l = tid & 63;
  const int b = m >> 12, lseq = m & 4095;
  const int c0 = h * 256 + l * 4;
  const size_t base = (size_t)m * 1024 + c0;
  float x[5][4];
  fir_otf(vc, w3t, w7t, w1g, b, lseq, c0, x[0], x[1], x[4]);
  {
    us4 v2 = *(const us4*)&fl[base];
    us4 v3 = *(const us4*)&dlt[base];
#pragma unroll
    for (int e = 0; e < 4; ++e) { x[2][e] = bf2f(v2[e]); x[3][e] = bf2f(v3[e]); }
  }
  float s1[5], s2[5], mx[5];
#pragma unroll
  for (int br = 0; br < 5; ++br) {
    float a = 0.f, bq = 0.f, m_ = -1e30f;
#pragma unroll
    for (int e = 0; e < 4; ++e) {
      a += x[br][e]; bq += x[br][e] * x[br][e]; m_ = fmaxf(m_, x[br][e]);
    }
    s1[br] = wsum(a); s2[br] = wsum(bq); mx[br] = wmax(m_);
  }
  float ent[5];
#pragma unroll
  for (int br = 0; br < 5; ++br) {
    float e_ = 0.f;
#pragma unroll
    for (int e = 0; e < 4; ++e) e_ += expf(x[br][e] - mx[br]);
    float es = wsum(e_);
    float hn = 0.f;
#pragma unroll
    for (int e = 0; e < 4; ++e) {
      float pv = expf(x[br][e] - mx[br]) / es;
      hn += pv * logf(pv + 1e-8f);
    }
    ent[br] = -wsum(hn);
  }
  float dt[10];
  {
    int pi = 0;
#pragma unroll
    for (int i = 0; i < 5; ++i)
#pragma unroll
      for (int j = i + 1; j < 5; ++j) {
        float d = 0.f;
#pragma unroll
        for (int e = 0; e < 4; ++e) d += x[i][e] * x[j][e];
        dt[pi] = wsum(d);
        ++pi;
      }
  }
  if (l == 0) {
    u16t* rp = router + (size_t)m * 1152 + 1024;
#pragma unroll
    for (int br = 0; br < 5; ++br) {
      float mean = s1[br] * (1.f / 256.f);
      float var = (s2[br] - s1[br] * s1[br] * (1.f / 256.f)) * (1.f / 255.f);
      rp[br * 16 + 0 + h] = f2bf(mean);
      rp[br * 16 + 4 + h] = f2bf(var);
      rp[br * 16 + 8 + h] = f2bf(mx[br]);
      rp[br * 16 + 12 + h] = f2bf(ent[br]);
    }
    int pi = 0;
#pragma unroll
    for (int i = 0; i < 5; ++i)
#pragma unroll
      for (int j = i + 1; j < 5; ++j) {
        float den = sqrtf(s2[i]) * sqrtf(s2[j]) + 1e-8f;
        rp[80 + pi * 4 + h] = f2bf(dt[pi] / den);
        ++pi;
      }
  }
  {
    f4 hv = *(const f4*)&hid[(size_t)m * 1024 + tid * 4];
    us4 hv4;
#pragma unroll
    for (int e = 0; e < 4; ++e) hv4[e] = f2bf(hv[e]);
    *(us4*)&router[(size_t)m * 1152 + tid * 4] = hv4;
  }
  if (tid < 8) router[(size_t)m * 1152 + 1144 + tid] = 0;
}

// ---------- softmax(precomputed logits) + floor + mix + RMSNorm ----------
__global__ __launch_bounds__(256) void route_mix(const float* __restrict__ logits,
    const u16t* __restrict__ vc, const float* __restrict__ w3t,
    const float* __restrict__ w7t, const float* __restrict__ w1g,
    const u16t* __restrict__ fl, const u16t* __restrict__ dlt,
    const float* __restrict__ normw, u16t* __restrict__ mixed) {
  const int m = blockIdx.x, tid = threadIdx.x;
  const int h = tid >> 6, l = tid & 63;
  float p5[5];
  {
    float lg[5];
#pragma unroll
    for (int n = 0; n < 5; ++n) lg[n] = logits[(size_t)m * 32 + h * 5 + n];
    float mxv = lg[0];
#pragma unroll
    for (int n = 1; n < 5; ++n) mxv = fmaxf(mxv, lg[n]);
    float es = 0.f, ev[5];
#pragma unroll
    for (int n = 0; n < 5; ++n) { ev[n] = expf(lg[n] - mxv); es += ev[n]; }
#pragma unroll
    for (int n = 0; n < 5; ++n) p5[n] = (ev[n] / es) * 0.95f + 0.01f;
  }
  const int b = m >> 12, lseq = m & 4095;
  const int c0 = h * 256 + l * 4;
  const size_t base = (size_t)m * 1024 + c0;
  float x[5][4];
  fir_otf(vc, w3t, w7t, w1g, b, lseq, c0, x[0], x[1], x[4]);
  {
    us4 v2 = *(const us4*)&fl[base];
    us4 v3 = *(const us4*)&dlt[base];
#pragma unroll
    for (int e = 0; e < 4; ++e) { x[2][e] = bf2f(v2[e]); x[3][e] = bf2f(v3[e]); }
  }
  float o[4] = {0.f, 0.f, 0.f, 0.f};
#pragma unroll
  for (int br = 0; br < 5; ++br)
#pragma unroll
    for (int e = 0; e < 4; ++e) o[e] += p5[br] * x[br][e];
  float ss = 0.f;
#pragma unroll
  for (int e = 0; e < 4; ++e) ss += o[e] * o[e];
  ss = wsum(ss);
  float sc = rsqrtf(ss * (1.f / 256.f) + 1e-5f);
  f4 nw = *(const f4*)&normw[l * 4];
  us4 ov;
#pragma unroll
  for (int e = 0; e < 4; ++e) ov[e] = f2bf(o[e] * sc * nw[e]);
  *(us4*)&mixed[base] = ov;
}

// ---------- launcher ----------
extern "C" void kernel_launch(void* const* d_in, const int* in_sizes, int n_in,
                              void* d_out, int out_size, void* d_ws, size_t ws_size,
                              hipStream_t stream) {
  (void)in_sizes; (void)n_in; (void)out_size; (void)ws_size;
  const float* hid = (const float*)d_in[0];
  const float* Wq = (const float*)d_in[1];
  const float* Wk = (const float*)d_in[2];
  const float* Wv = (const float*)d_in[3];
  const float* wqc = (const float*)d_in[4];
  const float* wkc = (const float*)d_in[5];
  const float* wvc = (const float*)d_in[6];
  const float* Wb = (const float*)d_in[7];
  const float* fsw = (const float*)d_in[8];
  const float* fmw = (const float*)d_in[9];
  const float* flw = (const float*)d_in[10];
  const float* fiw = (const float*)d_in[11];
  const float* W1 = (const float*)d_in[12];
  const float* b1 = (const float*)d_in[13];
  const float* W2 = (const float*)d_in[14];
  const float* b2 = (const float*)d_in[15];
  const float* nwt = (const float*)d_in[16];
  const float* Wo = (const float*)d_in[17];
  float* out = (float*)d_out;

  char* wsp = (char*)d_ws;
  const size_t S = (size_t)2 * 4096 * 1024 * 2;  // 16 MiB per (B,L,D) bf16 buffer
  u16t* ql = (u16t*)(wsp + 0 * S);
  u16t* kl = (u16t*)(wsp + 1 * S);
  u16t* vl = (u16t*)(wsp + 2 * S);
  u16t* qc = (u16t*)(wsp + 3 * S);
  u16t* kc = (u16t*)(wsp + 4 * S);
  u16t* vc = (u16t*)(wsp + 5 * S);
  u16t* ubuf = (u16t*)(wsp + 6 * S);
  u16t* wbuf = (u16t*)(wsp + 7 * S);
  char* p = wsp + 8 * S;
  u16t* router = (u16t*)p; p += (size_t)8192 * 1152 * 2;
  u16t* hrt = (u16t*)p;    p += (size_t)8192 * 2304 * 2;
  u16t* w1p = (u16t*)p;    p += (size_t)2304 * 1152 * 2;
  u16t* wob = (u16t*)p;    p += (size_t)1024 * 1024 * 2;
  u16t* w2b = (u16t*)p;    p += (size_t)32 * 2304 * 2;
  float* logits = (float*)p; p += (size_t)8192 * 32 * 4;
  float* w3t = (float*)p;  p += (size_t)3 * 1024 * 4;
  float* w7t = (float*)p;  p += (size_t)7 * 1024 * 4;
  // buffer reuse (lifetime-checked):
  u16t* hidb = qc;          // dead before conv writes qc
  u16t* wqb = kc;           // dead before conv writes kc
  u16t* wkb = kc + 1048576;
  u16t* wvb = kc + 2097152;
  u16t* kbeta = ql;   // ql dead after conv; kbeta dead after chunk_uw
  u16t* vbeta = kl;   // kl dead after conv; vbeta dead after chunk_uw
  u16t* dlt = kl;     // scan output
  u16t* f_l = vl;     // vl dead after conv; written by scan-shadow FIR
  u16t* mixed = wbuf; // wbuf (wg) dead after scan

  dim3 blk(256);
  pack_all<<<dim3(11304), blk, 0, stream>>>(hid, Wq, Wk, Wv, fsw, fmw,
                                            hidb, wqb, wkb, wvb, w3t, w7t);
  gemm_qkv3<<<dim3(8, 64, 3), blk, 0, stream>>>(hidb, wqb, wkb, wvb, ql, kl, vl);
  conv4_silu<<<dim3(64, 8, 3), blk, 0, stream>>>(ql, kl, vl, wqc, wkc, wvc, qc, kc, vc);
  prep_kernel<<<dim3(8192), blk, 0, stream>>>(qc, kc, vc, hid, Wb, kbeta, vbeta);
  chunk_uw<<<dim3(1024), blk, 0, stream>>>(kc, kbeta, vbeta, ubuf, wbuf);
  delta_scan<<<dim3(752), blk, 0, stream>>>(qc, kc, ubuf, wbuf, dlt, vc, flw, f_l,
                                            W1, w1p, Wo, wob, W2, w2b);
  features_kernel<<<dim3(8192), blk, 0, stream>>>(hid, vc, w3t, w7t, fiw, f_l, dlt, router);
  gemm_bt<false, 1><<<dim3(18, 64), blk, 0, stream>>>(router, w1p, hrt, b1, 1152, 1152, 1152, 2304);
  logits_gemm<<<dim3(64), blk, 0, stream>>>(hrt, w2b, b2, logits);
  route_mix<<<dim3(8192), blk, 0, stream>>>(logits, vc, w3t, w7t, fiw, f_l, dlt, nwt, mixed);
  gemm_bt<true, 0><<<dim3(8, 64), blk, 0, stream>>>(mixed, wob, out, nullptr, 1024, 1024, 1024, 1024);
}

// Round 15
// 967.096 us; speedup vs baseline: 1.6595x; 1.0261x over previous
//
#include <hip/hip_runtime.h>
#include <stdint.h>

// ---------- types / helpers ----------
typedef unsigned short u16t;
typedef u16t us4 __attribute__((ext_vector_type(4)));
typedef u16t us8 __attribute__((ext_vector_type(8)));
typedef __bf16 bf8v __attribute__((ext_vector_type(8)));
typedef float f4 __attribute__((ext_vector_type(4)));

#define MFMA(a, b, c) __builtin_amdgcn_mfma_f32_16x16x32_bf16((a), (b), (c), 0, 0, 0)
#define GLOAD_LDS16(g, l) __builtin_amdgcn_global_load_lds( \
    (const __attribute__((address_space(1))) void*)(g),     \
    (__attribute__((address_space(3))) void*)(l), 16, 0, 0)

__device__ __forceinline__ float bf2f(u16t u) {
  union { unsigned int i; float f; } c; c.i = ((unsigned int)u) << 16; return c.f;
}
__device__ __forceinline__ u16t f2bf(float f) {
  union { float f; unsigned int i; } c; c.f = f;
  return (u16t)((c.i + 0x7FFFu + ((c.i >> 16) & 1u)) >> 16);
}
__device__ __forceinline__ float wsum(float v) {
#pragma unroll
  for (int o = 32; o > 0; o >>= 1) v += __shfl_xor(v, o);
  return v;
}
__device__ __forceinline__ float wmax(float v) {
#pragma unroll
  for (int o = 32; o > 0; o >>= 1) v = fmaxf(v, __shfl_xor(v, o));
  return v;
}

// ---------- pack hid+Wq+Wk+Wv f32->bf16 + transpose small FIR weights ----------
__global__ __launch_bounds__(256) void pack_all(const float* __restrict__ hid,
    const float* __restrict__ Wq, const float* __restrict__ Wk, const float* __restrict__ Wv,
    const float* __restrict__ fsw, const float* __restrict__ fmw,
    u16t* __restrict__ hidb, u16t* __restrict__ wqb, u16t* __restrict__ wkb,
    u16t* __restrict__ wvb, float* __restrict__ w3t, float* __restrict__ w7t) {
  const int g = blockIdx.x * 256 + threadIdx.x;
  if (g < 2883584) {  // f4-group packs
    const float* src; u16t* dst; int off;
    if (g < 2097152) { src = hid; dst = hidb; off = g; }
    else if (g < 2359296) { src = Wq; dst = wqb; off = g - 2097152; }
    else if (g < 2621440) { src = Wk; dst = wkb; off = g - 2359296; }
    else { src = Wv; dst = wvb; off = g - 2621440; }
    f4 v = *(const f4*)&src[(size_t)off * 4];
    us4 o;
#pragma unroll
    for (int e = 0; e < 4; ++e) o[e] = f2bf(v[e]);
    *(us4*)&dst[(size_t)off * 4] = o;
    return;
  }
  int idx = g - 2883584;  // scalar transposes (one-time, tiny)
  if (idx < 3072) {
    int j = idx >> 10, c = idx & 1023;
    w3t[idx] = fsw[c * 3 + j];
  } else if (idx < 10240) {
    int idx2 = idx - 3072;
    int j = idx2 / 1024, c = idx2 & 1023;
    w7t[idx2] = fmw[c * 7 + j];
  }
}

// ---------- GEMM (all-bf16 operands): C[M,N] = A[M,K] @ Bt[N,K]^T ----------
template <bool CF32, int EPI>
__device__ __forceinline__ void gemm_body(const u16t* __restrict__ A,
    const u16t* __restrict__ Bt, void* __restrict__ Cv, const float* __restrict__ bias,
    int K, int lda, int ldb, int ldc, int m0, int n0) {
  __shared__ u16t As[128][32];
  __shared__ u16t Bs[128][32];
  const int tid = threadIdx.x;
  const int wv = tid >> 6, l = tid & 63;
  const int wr = wv >> 1, wc = wv & 1;
  const int lr = l & 15, kg8 = (l >> 4) * 8, rg4 = (l >> 4) * 4;
  const f4 zf = {0.f, 0.f, 0.f, 0.f};
  f4 acc[4][4];
#pragma unroll
  for (int i = 0; i < 4; ++i)
#pragma unroll
    for (int j = 0; j < 4; ++j) acc[i][j] = zf;

  const u16t* ga = A + (size_t)(m0 + wv * 32 + (l >> 2)) * lda + (l & 3) * 8;
  const u16t* gb = Bt + (size_t)(n0 + wv * 32 + (l >> 2)) * ldb + (l & 3) * 8;
  u16t* la0 = &As[wv * 32][0];
  u16t* la1 = &As[wv * 32 + 16][0];
  u16t* lb0 = &Bs[wv * 32][0];
  u16t* lb1 = &Bs[wv * 32 + 16][0];

  for (int kt = 0; kt < K; kt += 32) {
    GLOAD_LDS16(ga + kt, la0);
    GLOAD_LDS16(ga + (size_t)16 * lda + kt, la1);
    GLOAD_LDS16(gb + kt, lb0);
    GLOAD_LDS16(gb + (size_t)16 * ldb + kt, lb1);
    __syncthreads();
    bf8v af[4], bg[4];
#pragma unroll
    for (int f = 0; f < 4; ++f) af[f] = *(const bf8v*)&As[wr * 64 + f * 16 + lr][kg8];
#pragma unroll
    for (int f = 0; f < 4; ++f) bg[f] = *(const bf8v*)&Bs[wc * 64 + f * 16 + lr][kg8];
#pragma unroll
    for (int i = 0; i < 4; ++i)
#pragma unroll
      for (int j = 0; j < 4; ++j) acc[i][j] = MFMA(af[i], bg[j], acc[i][j]);
    __syncthreads();
  }
#pragma unroll
  for (int i = 0; i < 4; ++i) {
    const int rb = m0 + wr * 64 + i * 16 + rg4;
#pragma unroll
    for (int j = 0; j < 4; ++j) {
      const int cb = n0 + wc * 64 + j * 16 + lr;
#pragma unroll
      for (int r = 0; r < 4; ++r) {
        float x = acc[i][j][r];
        if (EPI == 1) {
          float xx = x + ((cb < 2288) ? bias[cb] : 0.f);
          x = 0.5f * xx * (1.f + erff(xx * 0.70710678118f));
        }
        if (CF32)
          ((float*)Cv)[(size_t)(rb + r) * ldc + cb] = x;
        else
          ((u16t*)Cv)[(size_t)(rb + r) * ldc + cb] = f2bf(x);
      }
    }
  }
}

template <bool CF32, int EPI>
__global__ __launch_bounds__(256) void gemm_bt(const u16t* __restrict__ Av,
    const u16t* __restrict__ Btv, void* __restrict__ Cv, const float* __restrict__ bias,
    int K, int lda, int ldb, int ldc) {
  gemm_body<CF32, EPI>(Av, Btv, Cv, bias, K, lda, ldb, ldc,
                       blockIdx.y * 128, blockIdx.x * 128);
}

__global__ __launch_bounds__(256) void gemm_qkv3(const u16t* __restrict__ A,
    const u16t* __restrict__ B0, const u16t* __restrict__ B1,
    const u16t* __restrict__ B2, u16t* __restrict__ C0, u16t* __restrict__ C1,
    u16t* __restrict__ C2v) {
  const int z = blockIdx.z;
  const u16t* Bt = (z == 0) ? B0 : ((z == 1) ? B1 : B2);
  u16t* C = (z == 0) ? C0 : ((z == 1) ? C1 : C2v);
  gemm_body<false, 0>(A, Bt, C, nullptr, 1024, 1024, 1024, 1024,
                      blockIdx.y * 128, blockIdx.x * 128);
}

// ---------- logits GEMM: logits[8192][32] = hrt[8192][2304] @ W2b[32][2304]^T + b2 ----------
__global__ __launch_bounds__(256) void logits_gemm(const u16t* __restrict__ hrt,
    const u16t* __restrict__ W2b, const float* __restrict__ b2, float* __restrict__ logits) {
  __shared__ u16t As[128][32];
  __shared__ u16t Bs[32][32];
  const int tid = threadIdx.x;
  const int wv = tid >> 6, l = tid & 63;
  const int lr = l & 15, kg8 = (l >> 4) * 8, rg4 = (l >> 4) * 4;
  const int m0 = blockIdx.x * 128;
  const f4 zf = {0.f, 0.f, 0.f, 0.f};
  f4 acc[2][2];
#pragma unroll
  for (int i = 0; i < 2; ++i)
#pragma unroll
    for (int j = 0; j < 2; ++j) acc[i][j] = zf;

  const u16t* ga = hrt + (size_t)(m0 + wv * 32 + (l >> 2)) * 2304 + (l & 3) * 8;
  const u16t* gb = W2b + (size_t)(l >> 2) * 2304 + (l & 3) * 8;
  u16t* la0 = &As[wv * 32][0];
  u16t* la1 = &As[wv * 32 + 16][0];

  for (int kt = 0; kt < 2304; kt += 32) {
    GLOAD_LDS16(ga + kt, la0);
    GLOAD_LDS16(ga + (size_t)16 * 2304 + kt, la1);
    if (wv == 0) {
      GLOAD_LDS16(gb + kt, &Bs[0][0]);
      GLOAD_LDS16(gb + (size_t)16 * 2304 + kt, &Bs[16][0]);
    }
    __syncthreads();
    bf8v af[2], bg[2];
#pragma unroll
    for (int f = 0; f < 2; ++f) af[f] = *(const bf8v*)&As[wv * 32 + f * 16 + lr][kg8];
#pragma unroll
    for (int f = 0; f < 2; ++f) bg[f] = *(const bf8v*)&Bs[f * 16 + lr][kg8];
#pragma unroll
    for (int i = 0; i < 2; ++i)
#pragma unroll
      for (int j = 0; j < 2; ++j) acc[i][j] = MFMA(af[i], bg[j], acc[i][j]);
    __syncthreads();
  }
#pragma unroll
  for (int i = 0; i < 2; ++i) {
    const int rb = m0 + wv * 32 + i * 16 + rg4;
#pragma unroll
    for (int j = 0; j < 2; ++j) {
      const int cb = j * 16 + lr;
#pragma unroll
      for (int r = 0; r < 4; ++r) {
        float x = acc[i][j][r];
        if (cb < 20) x += b2[cb];
        logits[(size_t)(rb + r) * 32 + cb] = x;
      }
    }
  }
}

// ---------- depthwise causal conv K=4 + SiLU (us8 cooperative staging) ----------
__global__ __launch_bounds__(256) void conv4_silu(
    const u16t* __restrict__ qlin, const u16t* __restrict__ klin, const u16t* __restrict__ vlin,
    const float* __restrict__ wq, const float* __restrict__ wk, const float* __restrict__ wvv,
    u16t* __restrict__ qc, u16t* __restrict__ kc, u16t* __restrict__ vc) {
  const int tid = threadIdx.x;
  const int l0 = blockIdx.x * 64;
  const int b = blockIdx.y >> 2, cb = blockIdx.y & 3;
  const int z = blockIdx.z;
  const u16t* in_ = (z == 0) ? qlin : ((z == 1) ? klin : vlin);
  const float* w_ = (z == 0) ? wq : ((z == 1) ? wk : wvv);
  u16t* out_ = (z == 0) ? qc : ((z == 1) ? kc : vc);
  const int c = cb * 256 + tid;
  __shared__ u16t sm[67][256];
  // cooperative us8 staging: 67 rows x 32 segs = 2144 us8 over 9 passes
  {
    const us8 z8 = {0, 0, 0, 0, 0, 0, 0, 0};
#pragma unroll
    for (int p = 0; p < 9; ++p) {
      int idx = p * 256 + tid;
      if (idx < 2144) {
        int row = idx >> 5, seg = (idx & 31) * 8;
        int ls = l0 - 3 + row;
        us8 v = (ls >= 0)
            ? *(const us8*)&in_[((size_t)b * 4096 + ls) * 1024 + cb * 256 + seg]
            : z8;
        *(us8*)&sm[row][seg] = v;
      }
    }
  }
  __syncthreads();
  f4 w4 = *(const f4*)&w_[c * 4];
  float x0 = bf2f(sm[0][tid]), x1 = bf2f(sm[1][tid]), x2 = bf2f(sm[2][tid]);
  for (int ll = 0; ll < 64; ++ll) {
    float x3 = bf2f(sm[ll + 3][tid]);
    float y = x0 * w4[0] + x1 * w4[1] + x2 * w4[2] + x3 * w4[3];
    y = y / (1.f + expf(-y));
    out_[((size_t)b * 4096 + l0 + ll) * 1024 + c] = f2bf(y);
    x0 = x1; x1 = x2; x2 = x3;
  }
}

// ---------- fused beta + l2norm(q,k) + kb/vb ----------
__global__ __launch_bounds__(256) void prep_kernel(u16t* __restrict__ qc, u16t* __restrict__ kc,
    const u16t* __restrict__ vc, const float* __restrict__ hid, const float* __restrict__ Wb,
    u16t* __restrict__ kbeta, u16t* __restrict__ vbeta) {
  const int m = blockIdx.x, tid = threadIdx.x;
  const int h = tid >> 6, l = tid & 63;
  float bacc = 0.f;
#pragma unroll
  for (int it = 0; it < 4; ++it) {
    int kk = l * 4 + it * 256;
    f4 hv = *(const f4*)&hid[(size_t)m * 1024 + kk];
    f4 wv4 = *(const f4*)&Wb[(size_t)h * 1024 + kk];
#pragma unroll
    for (int e = 0; e < 4; ++e) bacc += hv[e] * wv4[e];
  }
  const float bet = 1.f / (1.f + expf(-wsum(bacc)));
  const size_t base = (size_t)m * 1024 + h * 256 + l * 4;
  us4 q4 = *(const us4*)&qc[base];
  float qf[4]; float ss = 0.f;
#pragma unroll
  for (int e = 0; e < 4; ++e) { qf[e] = bf2f(q4[e]); ss += qf[e] * qf[e]; }
  float qsc = rsqrtf(wsum(ss) + 1e-12f);
  us4 qo;
#pragma unroll
  for (int e = 0; e < 4; ++e) qo[e] = f2bf(qf[e] * qsc);
  *(us4*)&qc[base] = qo;
  us4 k4 = *(const us4*)&kc[base];
  float kf[4]; ss = 0.f;
#pragma unroll
  for (int e = 0; e < 4; ++e) { kf[e] = bf2f(k4[e]); ss += kf[e] * kf[e]; }
  float ksc = rsqrtf(wsum(ss) + 1e-12f);
  us4 ko, kbo;
#pragma unroll
  for (int e = 0; e < 4; ++e) {
    float kn = kf[e] * ksc;
    ko[e] = f2bf(kn);
    kbo[e] = f2bf(kn * bet);
  }
  *(us4*)&kc[base] = ko;
  *(us4*)&kbeta[base] = kbo;
  us4 v4 = *(const us4*)&vc[base];
  us4 vo;
#pragma unroll
  for (int e = 0; e < 4; ++e) vo[e] = f2bf(bf2f(v4[e]) * bet);
  *(us4*)&vbeta[base] = vo;
}

// ---------- per-chunk triangular inverse, u = T@vb, w = T@kb (MFMA phase 1) ----------
__global__ __launch_bounds__(256) void chunk_uw(const u16t* __restrict__ kn,
    const u16t* __restrict__ kbeta, const u16t* __restrict__ vbeta,
    u16t* __restrict__ ug, u16t* __restrict__ wg) {
  const int tid = threadIdx.x;
  const int bh = blockIdx.x >> 7, ci = blockIdx.x & 127;
  const int b = bh >> 2, h = bh & 3;
  const int l0 = ci * 32;
  __shared__ u16t kns[32][264], kbs[32][264], vbs[32][264];
  __shared__ float attn_s[32][33];
  const int sr = tid >> 5, sd8 = (tid & 31) * 8;
  const size_t rowbase = (size_t)b * 4096 * 1024 + (size_t)h * 256;
#pragma unroll
  for (int i = 0; i < 4; ++i) {
    int r = i * 8 + sr;
    size_t g = rowbase + (size_t)(l0 + r) * 1024 + sd8;
    *(us8*)&kns[r][sd8] = *(const us8*)&kn[g];
    *(us8*)&kbs[r][sd8] = *(const us8*)&kbeta[g];
    *(us8*)&vbs[r][sd8] = *(const us8*)&vbeta[g];
  }
  __syncthreads();
  {
    const int wv = tid >> 6, l = tid & 63;
    const int lr = l & 15, kg8 = (l >> 4) * 8, rg4 = (l >> 4) * 4;
    const int rq = wv >> 1, rk = wv & 1;
    f4 t4 = {0.f, 0.f, 0.f, 0.f};
#pragma unroll
    for (int ks = 0; ks < 8; ++ks) {
      bf8v a = *(const bf8v*)&kbs[rq * 16 + lr][ks * 32 + kg8];
      bf8v bb = *(const bf8v*)&kns[rk * 16 + lr][ks * 32 + kg8];
      t4 = MFMA(a, bb, t4);
    }
    const int colj = rk * 16 + lr;
#pragma unroll
    for (int rr = 0; rr < 4; ++rr) {
      const int rowr = rq * 16 + rg4 + rr;
      attn_s[rowr][colj] = (colj < rowr) ? -t4[rr] : 0.f;
    }
  }
  __syncthreads();
  if (tid < 32) {
    const int j = tid;
    for (int i = 1; i < 32; ++i) {
      float aij = attn_s[i][j];
      float upd = 0.f;
#pragma unroll 1
      for (int k = 1; k < 31; ++k) {
        float aik = __shfl(aij, k);
        float akj = (k > j && k < i) ? attn_s[k][j] : 0.f;
        upd += aik * akj;
      }
      if (j < i) attn_s[i][j] = aij + upd;
    }
    attn_s[j][j] = 1.f;
  }
  __syncthreads();
  {
    const int r = tid >> 3, cg = (tid & 7) * 32;
    float ua[32], wa[32];
#pragma unroll
    for (int e = 0; e < 32; ++e) { ua[e] = 0.f; wa[e] = 0.f; }
    for (int j = 0; j < 32; ++j) {
      float a = attn_s[r][j];
#pragma unroll
      for (int e0 = 0; e0 < 32; e0 += 8) {
        us8 v8 = *(const us8*)&vbs[j][cg + e0];
        us8 k8 = *(const us8*)&kbs[j][cg + e0];
#pragma unroll
        for (int e = 0; e < 8; ++e) {
          ua[e0 + e] += a * bf2f(v8[e]);
          wa[e0 + e] += a * bf2f(k8[e]);
        }
      }
    }
    const size_t ob = ((size_t)bh * 4096 + l0 + r) * 256 + cg;
#pragma unroll
    for (int e0 = 0; e0 < 32; e0 += 8) {
      us8 pu, pw;
#pragma unroll
      for (int e = 0; e < 8; ++e) { pu[e] = f2bf(ua[e0 + e]); pw[e] = f2bf(wa[e0 + e]); }
      *(us8*)&ug[ob + e0] = pu;
      *(us8*)&wg[ob + e0] = pw;
    }
  }
}

// ---------- fused launch: 0-31 scan | 32-543 FIR-25 | 544-671 padW1 |
// 672-735 packWo | 736-751 packW2 ----------
__global__ __launch_bounds__(256, 1) void delta_scan(const u16t* __restrict__ qn,
    const u16t* __restrict__ kn, const u16t* __restrict__ ug, const u16t* __restrict__ wg,
    u16t* __restrict__ dout, const u16t* __restrict__ vc, const float* __restrict__ w25g,
    u16t* __restrict__ fl, const float* __restrict__ W1, u16t* __restrict__ W1p,
    const float* __restrict__ Wo, u16t* __restrict__ wob, const float* __restrict__ W2,
    u16t* __restrict__ W2b) {
  const int blk = blockIdx.x;
  const int tid = threadIdx.x;
  if (blk < 32) {  // ===== delta scan (r5-proven structure) =====
    const int bh = blk >> 2, vbidx = blk & 3;
    const int b = bh >> 2, h = bh & 3;
    const int c0 = vbidx * 64;
    const int wv = tid >> 6, l = tid & 63;
    const int lr = l & 15, kg8 = (l >> 4) * 8, rg4 = (l >> 4) * 4;

    __shared__ u16t qs[32][264], ks2[32][264], wss[32][264];
    __shared__ u16t kts[256][40];
    __shared__ u16t sbf[64][264];
    __shared__ u16t las[32][40];
    __shared__ u16t uts[64][40];

    {
      u16t* sp = &sbf[0][0];
      for (int i = tid; i < 64 * 264; i += 256) sp[i] = 0;
    }
    const f4 zf = {0.f, 0.f, 0.f, 0.f};
    f4 sacc[16];
#pragma unroll
    for (int d = 0; d < 16; ++d) sacc[d] = zf;
    __syncthreads();

    const u16t* qb = qn + (size_t)b * 4096 * 1024 + (size_t)h * 256;
    const u16t* knb = kn + (size_t)b * 4096 * 1024 + (size_t)h * 256;
    const u16t* ub = ug + (size_t)bh * 4096 * 256;
    const u16t* wb = wg + (size_t)bh * 4096 * 256;
    const int sr = tid >> 5, sd8 = (tid & 31) * 8;

    us8 pq[4], pk[4], pw[4];
    us4 pu0, pu1;
#pragma unroll
    for (int i = 0; i < 4; ++i) {
      const int r = i * 8 + sr;
      pq[i] = *(const us8*)(qb + (size_t)r * 1024 + sd8);
      pk[i] = *(const us8*)(knb + (size_t)r * 1024 + sd8);
      pw[i] = *(const us8*)(wb + (size_t)r * 256 + sd8);
    }
    pu0 = *(const us4*)(ub + (size_t)lr * 256 + c0 + wv * 16 + rg4);
    pu1 = *(const us4*)(ub + (size_t)(16 + lr) * 256 + c0 + wv * 16 + rg4);

    for (int ci = 0; ci < 128; ++ci) {
      const int l0 = ci * 32;
#pragma unroll
      for (int i = 0; i < 4; ++i) {
        const int r = i * 8 + sr;
        *(us8*)&qs[r][sd8] = pq[i];
        *(us8*)&ks2[r][sd8] = pk[i];
        *(us8*)&wss[r][sd8] = pw[i];
      }
      const us4 u0 = pu0, u1 = pu1;
      __syncthreads();
      if (ci < 127) {
        const int l1 = l0 + 32;
#pragma unroll
        for (int i = 0; i < 4; ++i) {
          const int r = i * 8 + sr;
          pq[i] = *(const us8*)(qb + (size_t)(l1 + r) * 1024 + sd8);
          pk[i] = *(const us8*)(knb + (size_t)(l1 + r) * 1024 + sd8);
          pw[i] = *(const us8*)(wb + (size_t)(l1 + r) * 256 + sd8);
        }
        pu0 = *(const us4*)(ub + (size_t)(l1 + lr) * 256 + c0 + wv * 16 + rg4);
        pu1 = *(const us4*)(ub + (size_t)(l1 + 16 + lr) * 256 + c0 + wv * 16 + rg4);
      }
      {
        const int dk = tid;
        const int swz = ((dk >> 3) & 3) << 3;
#pragma unroll
        for (int r = 0; r < 32; r += 2) {
          unsigned int lo = ks2[r][dk], hi = ks2[r + 1][dk];
          *(unsigned int*)&kts[dk][r ^ swz] = lo | (hi << 16);
        }
      }
      {
        const int rq = wv >> 1, rk = wv & 1;
        f4 t4 = zf;
#pragma unroll
        for (int ks = 0; ks < 8; ++ks) {
          bf8v a = *(const bf8v*)&qs[rq * 16 + lr][ks * 32 + kg8];
          bf8v bb = *(const bf8v*)&ks2[rk * 16 + lr][ks * 32 + kg8];
          t4 = MFMA(a, bb, t4);
        }
        const int colj = rk * 16 + lr;
#pragma unroll
        for (int rr = 0; rr < 4; ++rr) {
          const int rowr = rq * 16 + rg4 + rr;
          las[rowr][colj] = (colj <= rowr) ? f2bf(t4[rr]) : (u16t)0;
        }
      }
      f4 o0 = zf, o1 = zf;
      {
        f4 m0 = zf, m1 = zf;
#pragma unroll
        for (int ks = 0; ks < 8; ++ks) {
          bf8v a = *(const bf8v*)&sbf[wv * 16 + lr][ks * 32 + kg8];
          bf8v wb0 = *(const bf8v*)&wss[lr][ks * 32 + kg8];
          bf8v wb1 = *(const bf8v*)&wss[16 + lr][ks * 32 + kg8];
          bf8v qb0 = *(const bf8v*)&qs[lr][ks * 32 + kg8];
          bf8v qb1 = *(const bf8v*)&qs[16 + lr][ks * 32 + kg8];
          m0 = MFMA(a, wb0, m0);
          m1 = MFMA(a, wb1, m1);
          o0 = MFMA(a, qb0, o0);
          o1 = MFMA(a, qb1, o1);
        }
#pragma unroll
        for (int rt = 0; rt < 2; ++rt) {
          f4 mm = rt ? m1 : m0;
          const us4 uu = rt ? u1 : u0;
          const int r = rt * 16 + lr;
#pragma unroll
          for (int rr = 0; rr < 4; ++rr)
            uts[wv * 16 + rg4 + rr][r] = f2bf(bf2f(uu[rr]) - mm[rr]);
        }
      }
      __syncthreads();
      {
        bf8v a2 = *(const bf8v*)&uts[wv * 16 + lr][kg8];
        {
          bf8v lb0 = *(const bf8v*)&las[lr][kg8];
          bf8v lb1 = *(const bf8v*)&las[16 + lr][kg8];
          o0 = MFMA(a2, lb0, o0);
          o1 = MFMA(a2, lb1, o1);
        }
#pragma unroll
        for (int rt = 0; rt < 2; ++rt) {
          f4 oo = rt ? o1 : o0;
          const int r = rt * 16 + lr;
          us4 st;
#pragma unroll
          for (int rr = 0; rr < 4; ++rr) st[rr] = f2bf(oo[rr]);
          *(us4*)(dout + ((size_t)(b * 4096 + l0 + r) * 4 + h) * 256 + c0 + wv * 16 + rg4) = st;
        }
#pragma unroll
        for (int d = 0; d < 16; ++d) {
          const int swzd = ((2 * d + (lr >> 3)) & 3) << 3;
          bf8v bb = *(const bf8v*)&kts[d * 16 + lr][kg8 ^ swzd];
          sacc[d] = MFMA(a2, bb, sacc[d]);
        }
#pragma unroll
        for (int d = 0; d < 16; ++d) {
#pragma unroll
          for (int rr = 0; rr < 4; ++rr)
            sbf[wv * 16 + rg4 + rr][d * 16 + lr] = f2bf(sacc[d][rr]);
        }
      }
      __syncthreads();
    }
    return;
  }
  if (blk < 544) {  // ===== 25-tap FIR (fl branch), us8 cooperative staging =====
    const int fb = blk - 32;
    const int l0 = (fb & 63) * 64;
    const int by = fb >> 6;
    const int b = by >> 2, cb = by & 3;
    const int c = cb * 256 + tid;
    __shared__ u16t sm[88][256];
    {
      const us8 z8 = {0, 0, 0, 0, 0, 0, 0, 0};
#pragma unroll
      for (int p = 0; p < 11; ++p) {
        int idx = p * 256 + tid;
        if (idx < 2816) {
          int row = idx >> 5, seg = (idx & 31) * 8;
          int ls = l0 - 24 + row;
          us8 v = (ls >= 0)
              ? *(const us8*)&vc[((size_t)b * 4096 + ls) * 1024 + cb * 256 + seg]
              : z8;
          *(us8*)&sm[row][seg] = v;
        }
      }
    }
    __syncthreads();
    float w25[25];
#pragma unroll
    for (int j = 0; j < 25; ++j) w25[j] = w25g[c * 25 + j];
    float x[25];
#pragma unroll
    for (int j = 0; j < 25; ++j) x[j] = bf2f(sm[j][tid]);
    for (int ll = 0; ll < 64; ++ll) {
      float yl = 0.f;
#pragma unroll
      for (int j = 0; j < 25; ++j) yl += x[j] * w25[j];
      fl[((size_t)b * 4096 + l0 + ll) * 1024 + c] = f2bf(yl);
      if (ll < 63) {
#pragma unroll
        for (int j = 0; j < 24; ++j) x[j] = x[j + 1];
        x[24] = bf2f(sm[ll + 25][tid]);
      }
    }
    return;
  }
  if (blk < 672) {  // ===== pad W1 f32->bf16 =====
    for (size_t idx = (size_t)(blk - 544) * 256 + tid; idx < (size_t)2304 * 1152;
         idx += (size_t)128 * 256) {
      int n = (int)(idx / 1152), k = (int)(idx % 1152);
      W1p[idx] = (n < 2288 && k < 1144) ? f2bf(W1[(size_t)n * 1144 + k]) : (u16t)0;
    }
    return;
  }
  if (blk < 736) {  // ===== pack Wo f32->bf16 =====
    for (size_t i = (size_t)(blk - 672) * 256 + tid; i < 262144; i += (size_t)64 * 256) {
      f4 v = *(const f4*)&Wo[i * 4];
      us4 o;
#pragma unroll
      for (int e = 0; e < 4; ++e) o[e] = f2bf(v[e]);
      *(us4*)&wob[i * 4] = o;
    }
    return;
  }
  // ===== pack W2 [20][2288] f32 -> W2b [32][2304] bf16 zero-padded =====
  for (size_t idx = (size_t)(blk - 736) * 256 + tid; idx < (size_t)32 * 2304;
       idx += (size_t)16 * 256) {
    int n = (int)(idx / 2304), k = (int)(idx % 2304);
    W2b[idx] = (n < 20 && k < 2288) ? f2bf(W2[(size_t)n * 2288 + k]) : (u16t)0;
  }
}

// ---------- on-the-fly small FIR branches (K=3,7,1), transposed weights ----------
__device__ __forceinline__ void fir_otf(const u16t* __restrict__ vc,
    const float* __restrict__ w3t, const float* __restrict__ w7t,
    const float* __restrict__ w1g, int b, int lseq, int c0,
    float ys[4], float ym[4], float yi[4]) {
  float xs[7][4];
#pragma unroll
  for (int j = 0; j < 7; ++j) {
    int ls = lseq - 6 + j;
    if (ls >= 0) {
      us4 v = *(const us4*)&vc[((size_t)b * 4096 + ls) * 1024 + c0];
#pragma unroll
      for (int e = 0; e < 4; ++e) xs[j][e] = bf2f(v[e]);
    } else {
#pragma unroll
      for (int e = 0; e < 4; ++e) xs[j][e] = 0.f;
    }
  }
  f4 w3v[3], w7v[7], w1v;
#pragma unroll
  for (int j = 0; j < 3; ++j) w3v[j] = *(const f4*)&w3t[j * 1024 + c0];
#pragma unroll
  for (int j = 0; j < 7; ++j) w7v[j] = *(const f4*)&w7t[j * 1024 + c0];
  w1v = *(const f4*)&w1g[c0];
#pragma unroll
  for (int e = 0; e < 4; ++e) {
    ys[e] = xs[4][e] * w3v[0][e] + xs[5][e] * w3v[1][e] + xs[6][e] * w3v[2][e];
    float m_ = 0.f;
#pragma unroll
    for (int j = 0; j < 7; ++j) m_ += xs[j][e] * w7v[j][e];
    ym[e] = m_;
    yi[e] = xs[6][e] * w1v[e];
  }
}

// ---------- per-(b,l): stats + entropy + cross -> router_in ----------
__global__ __launch_bounds__(256) void features_kernel(const float* __restrict__ hid,
    const u16t* __restrict__ vc, const float* __restrict__ w3t, const float* __restrict__ w7t,
    const float* __restrict__ w1g, const u16t* __restrict__ fl, const u16t* __restrict__ dlt,
    u16t* __restrict__ router) {
  const int m = blockIdx.x, tid = threadIdx.x;
  const int h = tid >> 6, l = tid & 63;
  const int b = m >> 12, lseq = m & 4095;
  const int c0 = h * 256 + l * 4;
  const size_t base = (size_t)m * 1024 + c0;
  float x[5][4];
  fir_otf(vc, w3t, w7t, w1g, b, lseq, c0, x[0], x[1], x[4]);
  {
    us4 v2 = *(const us4*)&fl[base];
    us4 v3 = *(const us4*)&dlt[base];
#pragma unroll
    for (int e = 0; e < 4; ++e) { x[2][e] = bf2f(v2[e]); x[3][e] = bf2f(v3[e]); }
  }
  float s1[5], s2[5], mx[5];
#pragma unroll
  for (int br = 0; br < 5; ++br) {
    float a = 0.f, bq = 0.f, m_ = -1e30f;
#pragma unroll
    for (int e = 0; e < 4; ++e) {
      a += x[br][e]; bq += x[br][e] * x[br][e]; m_ = fmaxf(m_, x[br][e]);
    }
    s1[br] = wsum(a); s2[br] = wsum(bq); mx[br] = wmax(m_);
  }
  float ent[5];
#pragma unroll
  for (int br = 0; br < 5; ++br) {
    float e_ = 0.f;
#pragma unroll
    for (int e = 0; e < 4; ++e) e_ += expf(x[br][e] - mx[br]);
    float es = wsum(e_);
    float hn = 0.f;
#pragma unroll
    for (int e = 0; e < 4; ++e) {
      float pv = expf(x[br][e] - mx[br]) / es;
      hn += pv * logf(pv + 1e-8f);
    }
    ent[br] = -wsum(hn);
  }
  float dt[10];
  {
    int pi = 0;
#pragma unroll
    for (int i = 0; i < 5; ++i)
#pragma unroll
      for (int j = i + 1; j < 5; ++j) {
        float d = 0.f;
#pragma unroll
        for (int e = 0; e < 4; ++e) d += x[i][e] * x[j][e];
        dt[pi] = wsum(d);
        ++pi;
      }
  }
  if (l == 0) {
    u16t* rp = router + (size_t)m * 1152 + 1024;
#pragma unroll
    for (int br = 0; br < 5; ++br) {
      float mean = s1[br] * (1.f / 256.f);
      float var = (s2[br] - s1[br] * s1[br] * (1.f / 256.f)) * (1.f / 255.f);
      rp[br * 16 + 0 + h] = f2bf(mean);
      rp[br * 16 + 4 + h] = f2bf(var);
      rp[br * 16 + 8 + h] = f2bf(mx[br]);
      rp[br * 16 + 12 + h] = f2bf(ent[br]);
    }
    int pi = 0;
#pragma unroll
    for (int i = 0; i < 5; ++i)
#pragma unroll
      for (int j = i + 1; j < 5; ++j) {
        float den = sqrtf(s2[i]) * sqrtf(s2[j]) + 1e-8f;
        rp[80 + pi * 4 + h] = f2bf(dt[pi] / den);
        ++pi;
      }
  }
  {
    f4 hv = *(const f4*)&hid[(size_t)m * 1024 + tid * 4];
    us4 hv4;
#pragma unroll
    for (int e = 0; e < 4; ++e) hv4[e] = f2bf(hv[e]);
    *(us4*)&router[(size_t)m * 1152 + tid * 4] = hv4;
  }
  if (tid < 8) router[(size_t)m * 1152 + 1144 + tid] = 0;
}

// ---------- softmax(precomputed logits) + floor + mix + RMSNorm ----------
__global__ __launch_bounds__(256) void route_mix(const float* __restrict__ logits,
    const u16t* __restrict__ vc, const float* __restrict__ w3t,
    const float* __restrict__ w7t, const float* __restrict__ w1g,
    const u16t* __restrict__ fl, const u16t* __restrict__ dlt,
    const float* __restrict__ normw, u16t* __restrict__ mixed) {
  const int m = blockIdx.x, tid = threadIdx.x;
  const int h = tid >> 6, l = tid & 63;
  float p5[5];
  {
    float lg[5];
#pragma unroll
    for (int n = 0; n < 5; ++n) lg[n] = logits[(size_t)m * 32 + h * 5 + n];
    float mxv = lg[0];
#pragma unroll
    for (int n = 1; n < 5; ++n) mxv = fmaxf(mxv, lg[n]);
    float es = 0.f, ev[5];
#pragma unroll
    for (int n = 0; n < 5; ++n) { ev[n] = expf(lg[n] - mxv); es += ev[n]; }
#pragma unroll
    for (int n = 0; n < 5; ++n) p5[n] = (ev[n] / es) * 0.95f + 0.01f;
  }
  const int b = m >> 12, lseq = m & 4095;
  const int c0 = h * 256 + l * 4;
  const size_t base = (size_t)m * 1024 + c0;
  float x[5][4];
  fir_otf(vc, w3t, w7t, w1g, b, lseq, c0, x[0], x[1], x[4]);
  {
    us4 v2 = *(const us4*)&fl[base];
    us4 v3 = *(const us4*)&dlt[base];
#pragma unroll
    for (int e = 0; e < 4; ++e) { x[2][e] = bf2f(v2[e]); x[3][e] = bf2f(v3[e]); }
  }
  float o[4] = {0.f, 0.f, 0.f, 0.f};
#pragma unroll
  for (int br = 0; br < 5; ++br)
#pragma unroll
    for (int e = 0; e < 4; ++e) o[e] += p5[br] * x[br][e];
  float ss = 0.f;
#pragma unroll
  for (int e = 0; e < 4; ++e) ss += o[e] * o[e];
  ss = wsum(ss);
  float sc = rsqrtf(ss * (1.f / 256.f) + 1e-5f);
  f4 nw = *(const f4*)&normw[l * 4];
  us4 ov;
#pragma unroll
  for (int e = 0; e < 4; ++e) ov[e] = f2bf(o[e] * sc * nw[e]);
  *(us4*)&mixed[base] = ov;
}

// ---------- launcher ----------
extern "C" void kernel_launch(void* const* d_in, const int* in_sizes, int n_in,
                              void* d_out, int out_size, void* d_ws, size_t ws_size,
                              hipStream_t stream) {
  (void)in_sizes; (void)n_in; (void)out_size; (void)ws_size;
  const float* hid = (const float*)d_in[0];
  const float* Wq = (const float*)d_in[1];
  const float* Wk = (const float*)d_in[2];
  const float* Wv = (const float*)d_in[3];
  const float* wqc = (const float*)d_in[4];
  const float* wkc = (const float*)d_in[5];
  const float* wvc = (const float*)d_in[6];
  const float* Wb = (const float*)d_in[7];
  const float* fsw = (const float*)d_in[8];
  const float* fmw = (const float*)d_in[9];
  const float* flw = (const float*)d_in[10];
  const float* fiw = (const float*)d_in[11];
  const float* W1 = (const float*)d_in[12];
  const float* b1 = (const float*)d_in[13];
  const float* W2 = (const float*)d_in[14];
  const float* b2 = (const float*)d_in[15];
  const float* nwt = (const float*)d_in[16];
  const float* Wo = (const float*)d_in[17];
  float* out = (float*)d_out;

  char* wsp = (char*)d_ws;
  const size_t S = (size_t)2 * 4096 * 1024 * 2;  // 16 MiB per (B,L,D) bf16 buffer
  u16t* ql = (u16t*)(wsp + 0 * S);
  u16t* kl = (u16t*)(wsp + 1 * S);
  u16t* vl = (u16t*)(wsp + 2 * S);
  u16t* qc = (u16t*)(wsp + 3 * S);
  u16t* kc = (u16t*)(wsp + 4 * S);
  u16t* vc = (u16t*)(wsp + 5 * S);
  u16t* ubuf = (u16t*)(wsp + 6 * S);
  u16t* wbuf = (u16t*)(wsp + 7 * S);
  char* p = wsp + 8 * S;
  u16t* router = (u16t*)p; p += (size_t)8192 * 1152 * 2;
  u16t* hrt = (u16t*)p;    p += (size_t)8192 * 2304 * 2;
  u16t* w1p = (u16t*)p;    p += (size_t)2304 * 1152 * 2;
  u16t* wob = (u16t*)p;    p += (size_t)1024 * 1024 * 2;
  u16t* w2b = (u16t*)p;    p += (size_t)32 * 2304 * 2;
  float* logits = (float*)p; p += (size_t)8192 * 32 * 4;
  float* w3t = (float*)p;  p += (size_t)3 * 1024 * 4;
  float* w7t = (float*)p;  p += (size_t)7 * 1024 * 4;
  // buffer reuse (lifetime-checked):
  u16t* hidb = qc;          // dead before conv writes qc
  u16t* wqb = kc;           // dead before conv writes kc
  u16t* wkb = kc + 1048576;
  u16t* wvb = kc + 2097152;
  u16t* kbeta = ql;   // ql dead after conv; kbeta dead after chunk_uw
  u16t* vbeta = kl;   // kl dead after conv; vbeta dead after chunk_uw
  u16t* dlt = kl;     // scan output
  u16t* f_l = vl;     // vl dead after conv; written by scan-shadow FIR
  u16t* mixed = wbuf; // wbuf (wg) dead after scan

  dim3 blk(256);
  pack_all<<<dim3(11304), blk, 0, stream>>>(hid, Wq, Wk, Wv, fsw, fmw,
                                            hidb, wqb, wkb, wvb, w3t, w7t);
  gemm_qkv3<<<dim3(8, 64, 3), blk, 0, stream>>>(hidb, wqb, wkb, wvb, ql, kl, vl);
  conv4_silu<<<dim3(64, 8, 3), blk, 0, stream>>>(ql, kl, vl, wqc, wkc, wvc, qc, kc, vc);
  prep_kernel<<<dim3(8192), blk, 0, stream>>>(qc, kc, vc, hid, Wb, kbeta, vbeta);
  chunk_uw<<<dim3(1024), blk, 0, stream>>>(kc, kbeta, vbeta, ubuf, wbuf);
  delta_scan<<<dim3(752), blk, 0, stream>>>(qc, kc, ubuf, wbuf, dlt, vc, flw, f_l,
                                            W1, w1p, Wo, wob, W2, w2b);
  features_kernel<<<dim3(8192), blk, 0, stream>>>(hid, vc, w3t, w7t, fiw, f_l, dlt, router);
  gemm_bt<false, 1><<<dim3(18, 64), blk, 0, stream>>>(router, w1p, hrt, b1, 1152, 1152, 1152, 2304);
  logits_gemm<<<dim3(64), blk, 0, stream>>>(hrt, w2b, b2, logits);
  route_mix<<<dim3(8192), blk, 0, stream>>>(logits, vc, w3t, w7t, fiw, f_l, dlt, nwt, mixed);
  gemm_bt<true, 0><<<dim3(8, 64), blk, 0, stream>>>(mixed, wob, out, nullptr, 1024, 1024, 1024, 1024);
}